// Round 1
// 1399.191 us; speedup vs baseline: 1.1232x; 1.1232x over previous
//
#include <hip/hip_runtime.h>
#include <hip/hip_bf16.h>
#include <math.h>

#define NB 16
#define NT 4096
#define ND 1024
#define NCC 128
#define LCH 64
#define NCHUNK 64
#define BTROWS 65536

typedef __bf16 v8bf __attribute__((ext_vector_type(8)));
typedef float  v4f  __attribute__((ext_vector_type(4)));

static __device__ __forceinline__ float sig_(float x){ return 1.0f/(1.0f + __expf(-x)); }
static __device__ __forceinline__ float dot4_(float4 a, float4 b){
    return a.x*b.x + a.y*b.y + a.z*b.z + a.w*b.w;
}

static __device__ __forceinline__ v8bf pack8(float4 a, float4 b){
    v8bf v;
    v[0]=(__bf16)a.x; v[1]=(__bf16)a.y; v[2]=(__bf16)a.z; v[3]=(__bf16)a.w;
    v[4]=(__bf16)b.x; v[5]=(__bf16)b.y; v[6]=(__bf16)b.z; v[7]=(__bf16)b.w;
    return v;
}

// async global->LDS, 16B per lane; lds dst is wave-uniform base (+lane*16 by HW)
static __device__ __forceinline__ void gload16(const void* g, void* l){
    __builtin_amdgcn_global_load_lds(
        (const __attribute__((address_space(1))) unsigned int*)g,
        (__attribute__((address_space(3))) unsigned int*)l, 16, 0, 0);
}

// ---------------- x -> bf16, fused alpha/beta GEMV ----------------
__global__ __launch_bounds__(256) void k_xcast(
    const float* __restrict__ x, const float* __restrict__ Wa,
    const float* __restrict__ Wb, const float* __restrict__ ba,
    const float* __restrict__ bb2, __bf16* __restrict__ xbf,
    float* __restrict__ ab, float* __restrict__ beb)
{
    const int tid = threadIdx.x;
    const int w = tid >> 6, lane = tid & 63;
    const size_t row = (size_t)blockIdx.x*4 + w;
    const float* xr = x + row*ND + lane*16;
    float4 f0 = ((const float4*)xr)[0];
    float4 f1 = ((const float4*)xr)[1];
    float4 f2 = ((const float4*)xr)[2];
    float4 f3 = ((const float4*)xr)[3];
    const float4* wa = (const float4*)(Wa + lane*16);
    const float4* wb = (const float4*)(Wb + lane*16);
    float da = dot4_(f0,wa[0]) + dot4_(f1,wa[1]) + dot4_(f2,wa[2]) + dot4_(f3,wa[3]);
    float db = dot4_(f0,wb[0]) + dot4_(f1,wb[1]) + dot4_(f2,wb[2]) + dot4_(f3,wb[3]);
    __bf16* xd = xbf + row*ND + lane*16;
    *(v8bf*)(xd)   = pack8(f0,f1);
    *(v8bf*)(xd+8) = pack8(f2,f3);
    #pragma unroll
    for (int m=1;m<64;m<<=1){ da += __shfl_xor(da,m,64); db += __shfl_xor(db,m,64); }
    if (lane == 0){
        ab[row]  = sig_(da + ba[0]);
        beb[row] = sig_(db + bb2[0]);
    }
}

// ---------------- W concat -> bf16 ----------------
__global__ __launch_bounds__(256) void k_wcast(
    const float* __restrict__ Wq, const float* __restrict__ Wk,
    const float* __restrict__ Wv, const float* __restrict__ Wg,
    __bf16* __restrict__ wbf)
{
    const int tid = threadIdx.x;
    const int w = tid >> 6, lane = tid & 63;
    const int row = blockIdx.x*4 + w;     // 0..511
    const float* src = (row < 128) ? Wq + (size_t)row*ND
                     : (row < 256) ? Wk + (size_t)(row-128)*ND
                     : (row < 384) ? Wv + (size_t)(row-256)*ND
                     :               Wg + (size_t)(row-384)*ND;
    const float4* s4 = (const float4*)(src + lane*16);
    float4 f0=s4[0], f1=s4[1], f2=s4[2], f3=s4[3];
    __bf16* xd = wbf + (size_t)row*ND + lane*16;
    *(v8bf*)(xd)   = pack8(f0,f1);
    *(v8bf*)(xd+8) = pack8(f2,f3);
}

// ---------------- GEMM1: [q k v g] = x_bf @ W_bf^T (m97 structure) ----------------
// 128x128 tile, BK=64, global_load_lds w/ XOR bank swizzle, XCD-aware decode.
__global__ __launch_bounds__(256) void k_proj2(
    const __bf16* __restrict__ xbf, const __bf16* __restrict__ wbf,
    const float* __restrict__ bq, const float* __restrict__ bk,
    const float* __restrict__ bv, const float* __restrict__ bg,
    float* __restrict__ qb, float* __restrict__ kb2,
    float* __restrict__ vb, float* __restrict__ gb)
{
    __shared__ __attribute__((aligned(16))) __bf16 As[128*64];
    __shared__ __attribute__((aligned(16))) __bf16 Bs[128*64];
    const int tid = threadIdx.x;
    const int lane = tid & 63, w = tid >> 6;
    const int q4 = lane >> 4, l16 = lane & 15;
    const int wm = w >> 1, wn = w & 1;

    // XCD-aware decode: 2048 blocks; XCD x gets m-tiles [x*64,(x+1)*64),
    // 4 consecutive n-tiles per m-tile -> x panel fetched once per XCD.
    const int f = blockIdx.x;
    const int xcd = f & 7, j = f >> 3;
    const int m0 = ((xcd << 6) + (j >> 2)) * 128;
    const int n0 = (j & 3) * 128;

    v4f acc[4][4] = {};

    for (int k0 = 0; k0 < ND; k0 += 64){
        __syncthreads();
        #pragma unroll
        for (int i=0;i<4;i++){
            const int r  = (w*4+i)*8 + (lane >> 3);
            const int ce = (((lane & 7) ^ (r & 7)) << 3);   // pre-swizzled source col (elems)
            gload16(xbf + (size_t)(m0 + r)*ND + k0 + ce, (char*)As + (w*4+i)*1024);
            gload16(wbf + (size_t)(n0 + r)*ND + k0 + ce, (char*)Bs + (w*4+i)*1024);
        }
        __syncthreads();
        #pragma unroll
        for (int ks=0; ks<2; ks++){
            v8bf af[4], bf[4];
            #pragma unroll
            for (int mf=0; mf<4; mf++){
                const int r = wm*64 + mf*16 + l16;
                af[mf] = *(const v8bf*)((const char*)As + r*128 + (((ks*4+q4) ^ (r&7)) << 4));
            }
            #pragma unroll
            for (int nf=0; nf<4; nf++){
                const int r = wn*64 + nf*16 + l16;
                bf[nf] = *(const v8bf*)((const char*)Bs + r*128 + (((ks*4+q4) ^ (r&7)) << 4));
            }
            #pragma unroll
            for (int mf=0; mf<4; mf++)
                #pragma unroll
                for (int nf=0; nf<4; nf++)
                    acc[mf][nf] = __builtin_amdgcn_mfma_f32_16x16x32_bf16(af[mf], bf[nf], acc[mf][nf], 0,0,0);
        }
    }

    #pragma unroll
    for (int mf=0; mf<4; mf++){
        #pragma unroll
        for (int nf=0; nf<4; nf++){
            const int ng  = n0 + wn*64 + nf*16 + l16;   // 0..511
            const int col = ng & 127;
            const int sel = ng >> 7;
            const float bias = (sel==0) ? bq[col] : (sel==1) ? bk[col]
                             : (sel==2) ? bv[col] : bg[col];
            #pragma unroll
            for (int r2=0;r2<4;r2++){
                const int m = m0 + wm*64 + mf*16 + q4*4 + r2;
                const float val = acc[mf][nf][r2] + bias;
                const size_t off = (size_t)m*NCC + col;
                if      (sel == 0) qb[off]  = val;
                else if (sel == 1) kb2[off] = val;
                else if (sel == 2) vb[off]  = val;
                else               gb[off]  = sig_(val);
            }
        }
    }
}

// ---------------- normalize k rows ----------------
__global__ __launch_bounds__(256) void k_knorm(float* __restrict__ kb){
    const int tid = threadIdx.x;
    const int w = tid >> 6, lane = tid & 63;
    const size_t row = (size_t)blockIdx.x*4 + w;
    float* kr = kb + row*NCC;
    float a = kr[lane], b = kr[lane+64];
    float ss = a*a + b*b;
    #pragma unroll
    for (int m=1;m<64;m<<=1) ss += __shfl_xor(ss, m, 64);
    float inv = 1.0f / fmaxf(sqrtf(ss), 1e-12f);
    kr[lane] = a*inv; kr[lane+64] = b*inv;
}

// ---------------- Phase A: per-chunk precompute (gamma, G, solve U/M, P^T, R) ----------------
__global__ __launch_bounds__(256) void k_phaseA(
    const float* __restrict__ kb, float* __restrict__ vb, float* __restrict__ Mb,
    const float* __restrict__ ab, const float* __restrict__ beb,
    float* __restrict__ lgb, __bf16* __restrict__ PTb, float* __restrict__ Rb)
{
    __shared__ __attribute__((aligned(16))) float Ksh[LCH*132];
    __shared__ __attribute__((aligned(16))) float Ush[LCH*132];
    __shared__ __attribute__((aligned(16))) float Msh[LCH*132];
    __shared__ __attribute__((aligned(16))) float Gsh[LCH*68];
    __shared__ float lgs[LCH], bsh[LCH], esh[LCH], gam[LCH];

    const int tid = threadIdx.x;
    const int b = blockIdx.x >> 6;
    const int c = blockIdx.x & 63;
    const size_t base = (size_t)b*NT + (size_t)c*LCH;

    if (tid < LCH){
        float la = __logf(fmaxf(ab[base+tid], 1e-30f));
        float ps = la;
        #pragma unroll
        for (int off=1; off<64; off<<=1){
            float o = __shfl_up(ps, off, 64);
            if ((tid & 63) >= off) ps += o;
        }
        lgs[tid] = ps;
        bsh[tid] = beb[base+tid];
    }
    {
        const int row = tid >> 2, seg = tid & 3;
        const float* ks = kb + (base+row)*NCC + seg*32;
        const float* vs = vb + (base+row)*NCC + seg*32;
        float* kd = &Ksh[row*132 + seg*32];
        float* vd = &Ush[row*132 + seg*32];
        #pragma unroll
        for (int i=0;i<32;i+=4){
            *(float4*)(kd+i) = *(const float4*)(ks+i);
            *(float4*)(vd+i) = *(const float4*)(vs+i);
        }
    }
    __syncthreads();
    if (tid < LCH){
        lgb[base+tid] = lgs[tid];
        esh[tid] = __expf(lgs[LCH-1] - lgs[tid]);
        gam[tid] = __expf(lgs[tid]);
    }
    // G[t][s] = exp(lg_t - lg_s) * (k_s . k_t), s <= t
    for (int idx = tid; idx < (LCH*(LCH+1))/2; idx += 256){
        int t = (int)((sqrtf(8.f*(float)idx + 1.f) - 1.f)*0.5f);
        while ((t+1)*(t+2)/2 <= idx) t++;
        while (t*(t+1)/2 > idx) t--;
        const int s = idx - (t*(t+1))/2;
        const float* k1 = &Ksh[s*132];
        const float* k2 = &Ksh[t*132];
        float dot = 0.f;
        #pragma unroll 8
        for (int j=0;j<NCC;j+=4){
            float4 u = *(const float4*)(k1+j);
            float4 v = *(const float4*)(k2+j);
            dot += u.x*v.x + u.y*v.y + u.z*v.z + u.w*v.w;
        }
        Gsh[t*68+s] = __expf(lgs[t]-lgs[s])*dot;
    }
    __syncthreads();
    // forward substitution: u_t = b_t(v_t - sum G u_s); m_t = b_t(gam_t k_t - sum G m_s)
    {
        const int half = tid >> 7, cix = tid & 127;
        for (int t=0;t<LCH;t++){
            float acc2 = 0.f;
            if (half == 0){
                for (int s=0;s<t;s++) acc2 += Gsh[t*68+s]*Ush[s*132+cix];
            } else {
                for (int s=0;s<t;s++) acc2 += Gsh[t*68+s]*Msh[s*132+cix];
            }
            float outv;
            if (half == 0) outv = bsh[t]*(Ush[t*132+cix] - acc2);
            else           outv = bsh[t]*(gam[t]*Ksh[t*132+cix] - acc2);
            if (half == 0) Ush[t*132+cix] = outv;
            else           Msh[t*132+cix] = outv;
            __syncthreads();
        }
    }
    // write U (over v) and M to global
    {
        const int row = tid >> 2, seg = tid & 3;
        float* ud = vb + (base+row)*NCC + seg*32;
        float* md = Mb + (base+row)*NCC + seg*32;
        #pragma unroll
        for (int i=0;i<32;i+=4){
            *(float4*)(ud+i) = *(const float4*)(&Ush[row*132+seg*32+i]);
            *(float4*)(md+i) = *(const float4*)(&Msh[row*132+seg*32+i]);
        }
    }
    // P^T[j][m] = gl*delta - sum_t e_t k_t[j] m_t[m];  R[i][j] = sum_t e_t u_t[i] k_t[j]
    const float gl = __expf(lgs[LCH-1]);
    const size_t pbase = ((size_t)(b*NCHUNK + c))*NCC*NCC;
    const int orow = tid >> 1;
    const int ohalf = (tid & 1)*64;
    #pragma unroll
    for (int sub=0; sub<4; sub++){
        float pacc[16];
        #pragma unroll
        for (int i=0;i<16;i++) pacc[i]=0.f;
        const int mb0 = ohalf + sub*16;
        for (int t=0;t<LCH;t++){
            const float sc = esh[t]*Ksh[t*132+orow];
            const float* mr = &Msh[t*132+mb0];
            #pragma unroll
            for (int i=0;i<16;i+=4){
                float4 mv = *(const float4*)(mr+i);
                pacc[i]   -= sc*mv.x; pacc[i+1] -= sc*mv.y;
                pacc[i+2] -= sc*mv.z; pacc[i+3] -= sc*mv.w;
            }
        }
        __bf16* pd = PTb + pbase + (size_t)orow*NCC + mb0;
        #pragma unroll
        for (int i=0;i<16;i++){
            float v = pacc[i];
            if (orow == mb0+i) v += gl;
            pd[i] = (__bf16)v;
        }
    }
    #pragma unroll
    for (int sub=0; sub<4; sub++){
        float racc[16];
        #pragma unroll
        for (int i=0;i<16;i++) racc[i]=0.f;
        const int jb0 = ohalf + sub*16;
        for (int t=0;t<LCH;t++){
            const float sc = esh[t]*Ush[t*132+orow];
            const float* kr = &Ksh[t*132+jb0];
            #pragma unroll
            for (int i=0;i<16;i+=4){
                float4 kv = *(const float4*)(kr+i);
                racc[i]   += sc*kv.x; racc[i+1] += sc*kv.y;
                racc[i+2] += sc*kv.z; racc[i+3] += sc*kv.w;
            }
        }
        float* rd = Rb + pbase + (size_t)orow*NCC + jb0;
        #pragma unroll
        for (int i=0;i<16;i++) rd[i] = racc[i];
    }
}

// ---------------- Phase B: S <- S*P + R over chunks; rows independent ----------------
__global__ __launch_bounds__(256) void k_phaseB(
    const __bf16* __restrict__ PTb, const float* __restrict__ Rb, float* __restrict__ Sb)
{
    __shared__ __attribute__((aligned(16))) float Ssh[16*132];
    const int tid = threadIdx.x;
    const int b = blockIdx.x >> 3, rb = blockIdx.x & 7;
    const int r0 = rb*16;
    const int lane = tid & 63, w = tid >> 6;
    const int q4 = lane >> 4, l16 = lane & 15;
    for (int i=tid; i<16*132; i+=256) Ssh[i] = 0.f;
    __syncthreads();
    for (int c=0; c<NCHUNK; c++){
        const size_t pbase = ((size_t)(b*NCHUNK + c))*NCC*NCC;
        {
            const int row = tid >> 4, cg = (tid & 15)*8;
            float* dst = Sb + pbase + (size_t)(r0+row)*NCC + cg;
            *(float4*)(dst)   = *(const float4*)(&Ssh[row*132+cg]);
            *(float4*)(dst+4) = *(const float4*)(&Ssh[row*132+cg+4]);
        }
        if (c == NCHUNK-1) break;
        v8bf af[4];
        #pragma unroll
        for (int ks=0; ks<4; ks++){
            const float* sr = &Ssh[l16*132 + ks*32 + q4*8];
            v8bf t;
            #pragma unroll
            for (int j=0;j<8;j++) t[j] = (__bf16)sr[j];
            af[ks] = t;
        }
        __syncthreads();
        v4f acc[2] = {};
        #pragma unroll
        for (int nt=0; nt<2; nt++){
            const int n0 = w*32 + nt*16;
            #pragma unroll
            for (int ks=0; ks<4; ks++){
                v8bf bf = *(const v8bf*)(PTb + pbase + (size_t)(n0+l16)*NCC + ks*32 + q4*8);
                acc[nt] = __builtin_amdgcn_mfma_f32_16x16x32_bf16(af[ks], bf, acc[nt], 0,0,0);
            }
        }
        #pragma unroll
        for (int nt=0; nt<2; nt++){
            const int n = w*32 + nt*16 + l16;
            #pragma unroll
            for (int r=0;r<4;r++){
                const int rowl = q4*4 + r;
                Ssh[rowl*132 + n] = acc[nt][r] + Rb[pbase + (size_t)(r0+rowl)*NCC + n];
            }
        }
        __syncthreads();
    }
}

// ---------------- Phase C: per-chunk outputs ----------------
__global__ __launch_bounds__(256) void k_phaseC(
    const float* __restrict__ qb, const float* __restrict__ kb,
    const float* __restrict__ Ub, const float* __restrict__ Mb,
    const float* __restrict__ Sb, const float* __restrict__ lgb,
    float* __restrict__ gb)
{
    __shared__ __attribute__((aligned(16))) float S0T[NCC*132];
    __shared__ __attribute__((aligned(16))) __bf16 Msh[LCH*136];
    __shared__ __attribute__((aligned(16))) __bf16 Qsh[LCH*136];
    __shared__ __attribute__((aligned(16))) __bf16 Ksh[LCH*136];
    __shared__ __attribute__((aligned(16))) __bf16 Wsh[LCH*136];
    __shared__ __attribute__((aligned(16))) float Ash[LCH*68];
    __shared__ float lgs[LCH];

    const int tid = threadIdx.x;
    const int b = blockIdx.x >> 6, c = blockIdx.x & 63;
    const size_t base = (size_t)b*NT + (size_t)c*LCH;
    const size_t pbase = ((size_t)(b*NCHUNK + c))*NCC*NCC;

    {
        const int i = tid >> 1, j0 = (tid & 1)*64;
        const float* src = Sb + pbase + (size_t)i*NCC + j0;
        #pragma unroll 4
        for (int j=0;j<64;j+=4){
            float4 v = *(const float4*)(src+j);
            S0T[(j0+j  )*132 + i] = v.x;
            S0T[(j0+j+1)*132 + i] = v.y;
            S0T[(j0+j+2)*132 + i] = v.z;
            S0T[(j0+j+3)*132 + i] = v.w;
        }
    }
    {
        const int row = tid >> 2, seg = tid & 3;
        const float* ms = Mb + (base+row)*NCC + seg*32;
        const float* qs = qb + (base+row)*NCC + seg*32;
        const float* ks = kb + (base+row)*NCC + seg*32;
        #pragma unroll 8
        for (int i=0;i<32;i++){
            Msh[row*136+seg*32+i] = (__bf16)ms[i];
            Qsh[row*136+seg*32+i] = (__bf16)qs[i];
            Ksh[row*136+seg*32+i] = (__bf16)ks[i];
        }
    }
    if (tid < LCH) lgs[tid] = lgb[base+tid];
    __syncthreads();

    // X1 = M S0^T ; W = U - X1  -> Wsh
    {
        const int tg = tid >> 5, ig = tid & 31;
        float acc[8][4] = {};
        for (int j=0;j<NCC;j++){
            float m8[8];
            #pragma unroll
            for (int r=0;r<8;r++) m8[r] = (float)Msh[(tg*8+r)*136 + j];
            float4 sv = *(const float4*)(&S0T[j*132 + ig*4]);
            #pragma unroll
            for (int r=0;r<8;r++){
                acc[r][0] += m8[r]*sv.x; acc[r][1] += m8[r]*sv.y;
                acc[r][2] += m8[r]*sv.z; acc[r][3] += m8[r]*sv.w;
            }
        }
        #pragma unroll
        for (int r=0;r<8;r++){
            const int t = tg*8+r;
            const float4 uv = *(const float4*)(Ub + (base+t)*NCC + ig*4);
            Wsh[t*136+ig*4+0] = (__bf16)(uv.x - acc[r][0]);
            Wsh[t*136+ig*4+1] = (__bf16)(uv.y - acc[r][1]);
            Wsh[t*136+ig*4+2] = (__bf16)(uv.z - acc[r][2]);
            Wsh[t*136+ig*4+3] = (__bf16)(uv.w - acc[r][3]);
        }
    }
    // O2 = diag(gamma) Q S0 (kept in registers)
    float o2[8][4];
    {
        const int tg = tid >> 5, jg = tid & 31;
        float acc[8][4] = {};
        for (int i=0;i<NCC;i++){
            float q8[8];
            #pragma unroll
            for (int r=0;r<8;r++) q8[r] = (float)Qsh[(tg*8+r)*136 + i];
            float s4[4];
            #pragma unroll
            for (int rr=0;rr<4;rr++) s4[rr] = S0T[(jg+32*rr)*132 + i];
            #pragma unroll
            for (int r=0;r<8;r++){
                acc[r][0] += q8[r]*s4[0]; acc[r][1] += q8[r]*s4[1];
                acc[r][2] += q8[r]*s4[2]; acc[r][3] += q8[r]*s4[3];
            }
        }
        #pragma unroll
        for (int r=0;r<8;r++){
            const float g = __expf(lgs[tg*8+r]);
            #pragma unroll
            for (int d=0;d<4;d++) o2[r][d] = g*acc[r][d];
        }
    }
    __syncthreads();
    // X2 = Q W^T -> A = tril_incl(scaled)
    {
        const int tg2 = tid >> 4, sg = tid & 15;
        float acc[4][4] = {};
        for (int i=0;i<NCC;i++){
            float qv[4], wv[4];
            #pragma unroll
            for (int r=0;r<4;r++){
                qv[r] = (float)Qsh[(tg2+16*r)*136 + i];
                wv[r] = (float)Wsh[(sg+16*r)*136 + i];
            }
            #pragma unroll
            for (int a2=0;a2<4;a2++){
                acc[a2][0] += qv[a2]*wv[0]; acc[a2][1] += qv[a2]*wv[1];
                acc[a2][2] += qv[a2]*wv[2]; acc[a2][3] += qv[a2]*wv[3];
            }
        }
        #pragma unroll
        for (int a2=0;a2<4;a2++){
            const int t = tg2 + 16*a2;
            #pragma unroll
            for (int b2=0;b2<4;b2++){
                const int s = sg + 16*b2;
                Ash[t*68+s] = (s <= t) ? __expf(lgs[t]-lgs[s])*acc[a2][b2] : 0.f;
            }
        }
    }
    __syncthreads();
    // O1 = A K ; o = (O1 + O2) * gate  -> gb (in place)
    {
        const int tg = tid >> 5, jg = tid & 31;
        float acc[8][4] = {};
        for (int s=0;s<LCH;s++){
            float a8[8];
            #pragma unroll
            for (int r=0;r<8;r++) a8[r] = Ash[(tg*8+r)*68 + s];
            float k4[4];
            #pragma unroll
            for (int rr=0;rr<4;rr++) k4[rr] = (float)Ksh[s*136 + jg + 32*rr];
            #pragma unroll
            for (int r=0;r<8;r++){
                acc[r][0] += a8[r]*k4[0]; acc[r][1] += a8[r]*k4[1];
                acc[r][2] += a8[r]*k4[2]; acc[r][3] += a8[r]*k4[3];
            }
        }
        #pragma unroll
        for (int r=0;r<8;r++){
            const int t = tg*8+r;
            #pragma unroll
            for (int d=0;d<4;d++){
                const int j = jg + 32*d;
                const size_t off = (base+t)*NCC + j;
                gb[off] = (acc[r][d] + o2[r][d]) * gb[off];
            }
        }
    }
}

// ---------------- GEMM2: out = obar @ Wo^T + bo ----------------
__global__ __launch_bounds__(256) void k_out(
    const float* __restrict__ ob, const float* __restrict__ Wo,
    const float* __restrict__ bo, float* __restrict__ out)
{
    __shared__ __attribute__((aligned(16))) __bf16 As[128*40];
    __shared__ __attribute__((aligned(16))) __bf16 Bs[64*40];
    const int tid = threadIdx.x;
    const int m0 = blockIdx.x*128, n0 = blockIdx.y*64;
    const int lane = tid & 63, w = tid >> 6;
    const int q4 = lane >> 4, l16 = lane & 15;
    const int arow = tid >> 1, aseg = tid & 1;
    const int brow = tid >> 2, bseg = tid & 3;
    const float* asrc = ob + (size_t)(m0+arow)*NCC;
    const float* bsrc = Wo + (size_t)(n0+brow)*NCC;

    v4f acc[2][4] = {};

    for (int k0=0; k0<NCC; k0+=32){
        __syncthreads();
        {
            float4 f0 = *(const float4*)(asrc + k0 + aseg*16);
            float4 f1 = *(const float4*)(asrc + k0 + aseg*16 + 4);
            float4 f2 = *(const float4*)(asrc + k0 + aseg*16 + 8);
            float4 f3 = *(const float4*)(asrc + k0 + aseg*16 + 12);
            *(v8bf*)(&As[arow*40 + aseg*16])     = pack8(f0,f1);
            *(v8bf*)(&As[arow*40 + aseg*16 + 8]) = pack8(f2,f3);
        }
        {
            float4 g0 = *(const float4*)(bsrc + k0 + bseg*8);
            float4 g1 = *(const float4*)(bsrc + k0 + bseg*8 + 4);
            *(v8bf*)(&Bs[brow*40 + bseg*8]) = pack8(g0,g1);
        }
        __syncthreads();
        v8bf af0 = *(const v8bf*)(&As[(w*32 + l16)*40 + q4*8]);
        v8bf af1 = *(const v8bf*)(&As[(w*32 + 16 + l16)*40 + q4*8]);
        #pragma unroll
        for (int nt=0; nt<4; nt++){
            v8bf bf = *(const v8bf*)(&Bs[(nt*16 + l16)*40 + q4*8]);
            acc[0][nt] = __builtin_amdgcn_mfma_f32_16x16x32_bf16(af0, bf, acc[0][nt], 0,0,0);
            acc[1][nt] = __builtin_amdgcn_mfma_f32_16x16x32_bf16(af1, bf, acc[1][nt], 0,0,0);
        }
    }
    #pragma unroll
    for (int mt=0; mt<2; mt++){
        #pragma unroll
        for (int nt=0; nt<4; nt++){
            const int n = n0 + nt*16 + l16;
            const float bias = bo[n];
            #pragma unroll
            for (int r=0;r<4;r++){
                const int m = m0 + w*32 + mt*16 + q4*4 + r;
                out[(size_t)m*ND + n] = acc[mt][nt][r] + bias;
            }
        }
    }
}

extern "C" void kernel_launch(void* const* d_in, const int* in_sizes, int n_in,
                              void* d_out, int out_size, void* d_ws, size_t ws_size,
                              hipStream_t stream)
{
    const float* x  = (const float*)d_in[0];
    const float* Wq = (const float*)d_in[1];
    const float* bq = (const float*)d_in[2];
    const float* Wk = (const float*)d_in[3];
    const float* bk = (const float*)d_in[4];
    const float* Wv = (const float*)d_in[5];
    const float* bv = (const float*)d_in[6];
    const float* Wa = (const float*)d_in[7];
    const float* ba = (const float*)d_in[8];
    const float* Wb = (const float*)d_in[9];
    const float* bb2= (const float*)d_in[10];
    const float* Wg = (const float*)d_in[11];
    const float* bg = (const float*)d_in[12];
    const float* Wo = (const float*)d_in[13];
    const float* bo = (const float*)d_in[14];

    char* ws = (char*)d_ws;
    const size_t SZ = (size_t)BTROWS*NCC*4;     // 33.55 MB
    float*  qb  = (float*)(ws + 0*SZ);
    float*  kb  = (float*)(ws + 1*SZ);
    float*  vb  = (float*)(ws + 2*SZ);          // v, overwritten by U
    float*  Mb  = (float*)(ws + 3*SZ);
    float*  gb  = (float*)(ws + 4*SZ);          // gate, overwritten by obar
    float*  Sb  = (float*)(ws + 5*SZ);          // 2*SZ: per-chunk incoming states
    float*  Rb  = (float*)(ws + 7*SZ);          // 2*SZ
    __bf16* PTb = (__bf16*)(ws + 9*SZ);         // SZ bytes (bf16)
    float*  ab  = (float*)(ws + 10*SZ);
    float*  beb = (float*)(ws + 10*SZ + 262144);
    float*  lgb = (float*)(ws + 10*SZ + 524288);
    // transient (pre-phaseA) reuse of Sb/Rb/PTb region:
    __bf16* xbf = (__bf16*)(ws + 5*SZ);         // 4*SZ bytes (65536x1024 bf16) = slots 5..9
    __bf16* wbf = (__bf16*)(ws + 9*SZ);         // 1 MB (512x1024 bf16), freed before phaseA writes PTb
    if (ws_size < 10*SZ + 786432) return;       // insufficient workspace

    dim3 blk(256);
    k_wcast <<<dim3(128),            blk, 0, stream>>>(Wq,Wk,Wv,Wg,wbf);
    k_xcast <<<dim3(BTROWS/4),       blk, 0, stream>>>(x,Wa,Wb,ba,bb2,xbf,ab,beb);
    k_proj2 <<<dim3(2048),           blk, 0, stream>>>(xbf,wbf,bq,bk,bv,bg,qb,kb,vb,gb);
    k_knorm <<<dim3(BTROWS/4),       blk, 0, stream>>>(kb);
    k_phaseA<<<dim3(NB*NCHUNK),      blk, 0, stream>>>(kb, vb, Mb, ab, beb, lgb, PTb, Rb);
    k_phaseB<<<dim3(NB*8),           blk, 0, stream>>>(PTb, Rb, Sb);
    k_phaseC<<<dim3(NB*NCHUNK),      blk, 0, stream>>>(qb, kb, vb, Mb, Sb, lgb, gb);
    k_out   <<<dim3(BTROWS/128, 16), blk, 0, stream>>>(gb, Wo, bo, (float*)d_out);
}

// Round 2
// 1207.978 us; speedup vs baseline: 1.3010x; 1.1583x over previous
//
#include <hip/hip_runtime.h>
#include <hip/hip_bf16.h>
#include <math.h>

#define NB 16
#define NT 4096
#define ND 1024
#define NCC 128
#define LCH 64
#define NCHUNK 64
#define BTROWS 65536

typedef __bf16 v8bf __attribute__((ext_vector_type(8)));
typedef float  v4f  __attribute__((ext_vector_type(4)));

static __device__ __forceinline__ float sig_(float x){ return 1.0f/(1.0f + __expf(-x)); }
static __device__ __forceinline__ float dot4_(float4 a, float4 b){
    return a.x*b.x + a.y*b.y + a.z*b.z + a.w*b.w;
}

static __device__ __forceinline__ v8bf pack8(float4 a, float4 b){
    v8bf v;
    v[0]=(__bf16)a.x; v[1]=(__bf16)a.y; v[2]=(__bf16)a.z; v[3]=(__bf16)a.w;
    v[4]=(__bf16)b.x; v[5]=(__bf16)b.y; v[6]=(__bf16)b.z; v[7]=(__bf16)b.w;
    return v;
}

// async global->LDS, 16B per lane; lds dst is wave-uniform base (+lane*16 by HW)
static __device__ __forceinline__ void gload16(const void* g, void* l){
    __builtin_amdgcn_global_load_lds(
        (const __attribute__((address_space(1))) unsigned int*)g,
        (__attribute__((address_space(3))) unsigned int*)l, 16, 0, 0);
}

// ---------------- x -> bf16, fused alpha/beta GEMV ----------------
__global__ __launch_bounds__(256) void k_xcast(
    const float* __restrict__ x, const float* __restrict__ Wa,
    const float* __restrict__ Wb, const float* __restrict__ ba,
    const float* __restrict__ bb2, __bf16* __restrict__ xbf,
    float* __restrict__ ab, float* __restrict__ beb)
{
    const int tid = threadIdx.x;
    const int w = tid >> 6, lane = tid & 63;
    const size_t row = (size_t)blockIdx.x*4 + w;
    const float* xr = x + row*ND + lane*16;
    float4 f0 = ((const float4*)xr)[0];
    float4 f1 = ((const float4*)xr)[1];
    float4 f2 = ((const float4*)xr)[2];
    float4 f3 = ((const float4*)xr)[3];
    const float4* wa = (const float4*)(Wa + lane*16);
    const float4* wb = (const float4*)(Wb + lane*16);
    float da = dot4_(f0,wa[0]) + dot4_(f1,wa[1]) + dot4_(f2,wa[2]) + dot4_(f3,wa[3]);
    float db = dot4_(f0,wb[0]) + dot4_(f1,wb[1]) + dot4_(f2,wb[2]) + dot4_(f3,wb[3]);
    __bf16* xd = xbf + row*ND + lane*16;
    *(v8bf*)(xd)   = pack8(f0,f1);
    *(v8bf*)(xd+8) = pack8(f2,f3);
    #pragma unroll
    for (int m=1;m<64;m<<=1){ da += __shfl_xor(da,m,64); db += __shfl_xor(db,m,64); }
    if (lane == 0){
        ab[row]  = sig_(da + ba[0]);
        beb[row] = sig_(db + bb2[0]);
    }
}

// ---------------- W concat -> bf16 ----------------
__global__ __launch_bounds__(256) void k_wcast(
    const float* __restrict__ Wq, const float* __restrict__ Wk,
    const float* __restrict__ Wv, const float* __restrict__ Wg,
    __bf16* __restrict__ wbf)
{
    const int tid = threadIdx.x;
    const int w = tid >> 6, lane = tid & 63;
    const int row = blockIdx.x*4 + w;     // 0..511
    const float* src = (row < 128) ? Wq + (size_t)row*ND
                     : (row < 256) ? Wk + (size_t)(row-128)*ND
                     : (row < 384) ? Wv + (size_t)(row-256)*ND
                     :               Wg + (size_t)(row-384)*ND;
    const float4* s4 = (const float4*)(src + lane*16);
    float4 f0=s4[0], f1=s4[1], f2=s4[2], f3=s4[3];
    __bf16* xd = wbf + (size_t)row*ND + lane*16;
    *(v8bf*)(xd)   = pack8(f0,f1);
    *(v8bf*)(xd+8) = pack8(f2,f3);
}

// ---------------- GEMM1: [q k v g] = x_bf @ W_bf^T (m97 structure) ----------------
__global__ __launch_bounds__(256) void k_proj2(
    const __bf16* __restrict__ xbf, const __bf16* __restrict__ wbf,
    const float* __restrict__ bq, const float* __restrict__ bk,
    const float* __restrict__ bv, const float* __restrict__ bg,
    float* __restrict__ qb, float* __restrict__ kb2,
    float* __restrict__ vb, float* __restrict__ gb)
{
    __shared__ __attribute__((aligned(16))) __bf16 As[128*64];
    __shared__ __attribute__((aligned(16))) __bf16 Bs[128*64];
    const int tid = threadIdx.x;
    const int lane = tid & 63, w = tid >> 6;
    const int q4 = lane >> 4, l16 = lane & 15;
    const int wm = w >> 1, wn = w & 1;

    const int f = blockIdx.x;
    const int xcd = f & 7, j = f >> 3;
    const int m0 = ((xcd << 6) + (j >> 2)) * 128;
    const int n0 = (j & 3) * 128;

    v4f acc[4][4] = {};

    for (int k0 = 0; k0 < ND; k0 += 64){
        __syncthreads();
        #pragma unroll
        for (int i=0;i<4;i++){
            const int r  = (w*4+i)*8 + (lane >> 3);
            const int ce = (((lane & 7) ^ (r & 7)) << 3);   // pre-swizzled source col (elems)
            gload16(xbf + (size_t)(m0 + r)*ND + k0 + ce, (char*)As + (w*4+i)*1024);
            gload16(wbf + (size_t)(n0 + r)*ND + k0 + ce, (char*)Bs + (w*4+i)*1024);
        }
        __syncthreads();
        #pragma unroll
        for (int ks=0; ks<2; ks++){
            v8bf af[4], bf[4];
            #pragma unroll
            for (int mf=0; mf<4; mf++){
                const int r = wm*64 + mf*16 + l16;
                af[mf] = *(const v8bf*)((const char*)As + r*128 + (((ks*4+q4) ^ (r&7)) << 4));
            }
            #pragma unroll
            for (int nf=0; nf<4; nf++){
                const int r = wn*64 + nf*16 + l16;
                bf[nf] = *(const v8bf*)((const char*)Bs + r*128 + (((ks*4+q4) ^ (r&7)) << 4));
            }
            #pragma unroll
            for (int mf=0; mf<4; mf++)
                #pragma unroll
                for (int nf=0; nf<4; nf++)
                    acc[mf][nf] = __builtin_amdgcn_mfma_f32_16x16x32_bf16(af[mf], bf[nf], acc[mf][nf], 0,0,0);
        }
    }

    #pragma unroll
    for (int mf=0; mf<4; mf++){
        #pragma unroll
        for (int nf=0; nf<4; nf++){
            const int ng  = n0 + wn*64 + nf*16 + l16;   // 0..511
            const int col = ng & 127;
            const int sel = ng >> 7;
            const float bias = (sel==0) ? bq[col] : (sel==1) ? bk[col]
                             : (sel==2) ? bv[col] : bg[col];
            #pragma unroll
            for (int r2=0;r2<4;r2++){
                const int m = m0 + wm*64 + mf*16 + q4*4 + r2;
                const float val = acc[mf][nf][r2] + bias;
                const size_t off = (size_t)m*NCC + col;
                if      (sel == 0) qb[off]  = val;
                else if (sel == 1) kb2[off] = val;
                else if (sel == 2) vb[off]  = val;
                else               gb[off]  = sig_(val);
            }
        }
    }
}

// ---------------- normalize k rows ----------------
__global__ __launch_bounds__(256) void k_knorm(float* __restrict__ kb){
    const int tid = threadIdx.x;
    const int w = tid >> 6, lane = tid & 63;
    const size_t row = (size_t)blockIdx.x*4 + w;
    float* kr = kb + row*NCC;
    float a = kr[lane], b = kr[lane+64];
    float ss = a*a + b*b;
    #pragma unroll
    for (int m=1;m<64;m<<=1) ss += __shfl_xor(ss, m, 64);
    float inv = 1.0f / fmaxf(sqrtf(ss), 1e-12f);
    kr[lane] = a*inv; kr[lane+64] = b*inv;
}

// ---------------- Phase A: per-chunk precompute ----------------
// Swizzled K in LDS (16B-granule XOR), barrier-free register-column solve,
// MFMA for P^T and R via transposed bf16 tiles (KT/EUT/EMT).
#define KSWZ(t, j)   ((t)*132 + ((((((j)>>2) ^ ((t)&7))) << 2) | ((j)&3)))
#define KSWZ4(t, j4) ((t)*132 + ((((j4) ^ ((t)&7))) << 2))
#define TSWZ(row, g) ((row)*72 + ((((g) ^ ((row)&7))) << 3))

#define SOLVE_LOOP(RHS_EXPR) \
    _Pragma("unroll") \
    for (int t=0;t<64;t++){ \
        const float* Gr = &Gsh[t*68]; \
        float s0=0.f,s1=0.f,s2=0.f,s3=0.f; \
        _Pragma("unroll") \
        for (int s4=0; s4+4<=t; s4+=4){ \
            float4 g = *(const float4*)(Gr+s4); \
            s0 += g.x*u[s4]; s1 += g.y*u[s4+1]; s2 += g.z*u[s4+2]; s3 += g.w*u[s4+3]; \
        } \
        _Pragma("unroll") \
        for (int s=(t & ~3); s<t; s++) s0 += Gr[s]*u[s]; \
        u[t] = bsh[t]*((RHS_EXPR) - ((s0+s1)+(s2+s3))); \
    }

__global__ __launch_bounds__(256) void k_phaseA(
    const float* __restrict__ kb, float* __restrict__ vb, __bf16* __restrict__ Mb,
    const float* __restrict__ ab, const float* __restrict__ beb,
    float* __restrict__ lgb, __bf16* __restrict__ PTb, float* __restrict__ Rb)
{
    __shared__ __attribute__((aligned(16))) float Ksh[LCH*132];   // swizzled (KSWZ)
    __shared__ __attribute__((aligned(16))) float Vsh[LCH*132];   // linear
    __shared__ __attribute__((aligned(16))) float Gsh[LCH*68];
    __shared__ __attribute__((aligned(16))) __bf16 KT [NCC*72];   // KT[j][t], swz TSWZ
    __shared__ __attribute__((aligned(16))) __bf16 EUT[NCC*72];   // e_t*u_t[i]
    __shared__ __attribute__((aligned(16))) __bf16 EMT[NCC*72];   // e_t*m_t[m]
    __shared__ float lgs[LCH], bsh[LCH], esh[LCH], gam[LCH];

    const int tid = threadIdx.x;
    const int b = blockIdx.x >> 6;
    const int c = blockIdx.x & 63;
    const size_t base = (size_t)b*NT + (size_t)c*LCH;

    if (tid < LCH){
        float la = __logf(fmaxf(ab[base+tid], 1e-30f));
        float ps = la;
        #pragma unroll
        for (int off=1; off<64; off<<=1){
            float o = __shfl_up(ps, off, 64);
            if ((tid & 63) >= off) ps += o;
        }
        lgs[tid] = ps;
        bsh[tid] = beb[base+tid];
    }
    // stage K (swizzled) and V (linear)
    {
        const int row = tid >> 2, seg = tid & 3;
        const float* ks = kb + (base+row)*NCC + seg*32;
        const float* vs = vb + (base+row)*NCC + seg*32;
        #pragma unroll
        for (int i=0;i<32;i+=4){
            float4 kv = *(const float4*)(ks+i);
            float4 vv = *(const float4*)(vs+i);
            *(float4*)(&Ksh[KSWZ4(row, ((seg*32+i)>>2))]) = kv;
            *(float4*)(&Vsh[row*132 + seg*32 + i]) = vv;
        }
    }
    __syncthreads();
    if (tid < LCH){
        lgb[base+tid] = lgs[tid];
        esh[tid] = __expf(lgs[LCH-1] - lgs[tid]);
        gam[tid] = __expf(lgs[tid]);
    }
    // G[t][s] = exp(lg_t - lg_s) * (k_s . k_t), s <= t
    for (int idx = tid; idx < (LCH*(LCH+1))/2; idx += 256){
        int t = (int)((sqrtf(8.f*(float)idx + 1.f) - 1.f)*0.5f);
        while ((t+1)*(t+2)/2 <= idx) t++;
        while (t*(t+1)/2 > idx) t--;
        const int s = idx - (t*(t+1))/2;
        float dot = 0.f;
        #pragma unroll 8
        for (int j4=0;j4<32;j4++){
            float4 u = *(const float4*)(&Ksh[KSWZ4(s,j4)]);
            float4 v = *(const float4*)(&Ksh[KSWZ4(t,j4)]);
            dot += u.x*v.x + u.y*v.y + u.z*v.z + u.w*v.w;
        }
        Gsh[t*68+s] = __expf(lgs[t]-lgs[s])*dot;
    }
    // KT[j][t] = bf16(k_t[j])  (transposed, swizzled rows)
    {
        const int j = tid & 127, th = tid >> 7;
        #pragma unroll
        for (int g=0; g<4; g++){
            const int t0 = th*32 + g*8;
            v8bf pk;
            #pragma unroll
            for (int e=0;e<8;e++) pk[e] = (__bf16)Ksh[KSWZ(t0+e, j)];
            *(v8bf*)(&KT[TSWZ(j, (t0>>3))]) = pk;
        }
    }
    __syncthreads();

    // barrier-free forward substitution; column lives in registers
    {
        const int half = tid >> 7, cix = tid & 127;
        float u[64];
        if (half == 0){
            SOLVE_LOOP(Vsh[t*132 + cix])
            #pragma unroll
            for (int t=0;t<64;t++) vb[(base+t)*NCC + cix] = u[t];   // U over v
            #pragma unroll
            for (int g=0; g<8; g++){
                v8bf pk;
                #pragma unroll
                for (int e=0;e<8;e++) pk[e] = (__bf16)(esh[g*8+e]*u[g*8+e]);
                *(v8bf*)(&EUT[TSWZ(cix, g)]) = pk;
            }
        } else {
            SOLVE_LOOP(gam[t]*Ksh[KSWZ(t, cix)])
            #pragma unroll
            for (int t=0;t<64;t++) Mb[(base+t)*NCC + cix] = (__bf16)u[t];
            #pragma unroll
            for (int g=0; g<8; g++){
                v8bf pk;
                #pragma unroll
                for (int e=0;e<8;e++) pk[e] = (__bf16)(esh[g*8+e]*u[g*8+e]);
                *(v8bf*)(&EMT[TSWZ(cix, g)]) = pk;
            }
        }
    }
    __syncthreads();

    // MFMA: P^T[j][m] = gl*delta - sum_t KT[j][t]*EMT[m][t]
    //       R  [i][j] =            sum_t EUT[i][t]*KT [j][t]
    {
        const int lane = tid & 63, w = tid >> 6;
        const int q4 = lane >> 4, l16 = lane & 15;
        const int wm = w >> 1, wn = w & 1;
        const float gl = gam[LCH-1];
        const size_t pbase = ((size_t)(b*NCHUNK + c))*NCC*NCC;
        {
            v4f pacc[4][4] = {};
            #pragma unroll
            for (int ks=0; ks<2; ks++){
                v8bf af[4], bf[4];
                #pragma unroll
                for (int mf=0; mf<4; mf++)
                    af[mf] = *(const v8bf*)(&KT[TSWZ(wm*64+mf*16+l16, ks*4+q4)]);
                #pragma unroll
                for (int nf=0; nf<4; nf++)
                    bf[nf] = *(const v8bf*)(&EMT[TSWZ(wn*64+nf*16+l16, ks*4+q4)]);
                #pragma unroll
                for (int mf=0; mf<4; mf++)
                    #pragma unroll
                    for (int nf=0; nf<4; nf++)
                        pacc[mf][nf] = __builtin_amdgcn_mfma_f32_16x16x32_bf16(af[mf], bf[nf], pacc[mf][nf], 0,0,0);
            }
            #pragma unroll
            for (int mf=0; mf<4; mf++){
                #pragma unroll
                for (int nf=0; nf<4; nf++){
                    const int m = wn*64 + nf*16 + l16;
                    #pragma unroll
                    for (int r=0;r<4;r++){
                        const int j = wm*64 + mf*16 + q4*4 + r;
                        float v = -pacc[mf][nf][r];
                        if (j == m) v += gl;
                        PTb[pbase + (size_t)j*NCC + m] = (__bf16)v;
                    }
                }
            }
        }
        {
            v4f racc[4][4] = {};
            #pragma unroll
            for (int ks=0; ks<2; ks++){
                v8bf af[4], bf[4];
                #pragma unroll
                for (int mf=0; mf<4; mf++)
                    af[mf] = *(const v8bf*)(&EUT[TSWZ(wm*64+mf*16+l16, ks*4+q4)]);
                #pragma unroll
                for (int nf=0; nf<4; nf++)
                    bf[nf] = *(const v8bf*)(&KT[TSWZ(wn*64+nf*16+l16, ks*4+q4)]);
                #pragma unroll
                for (int mf=0; mf<4; mf++)
                    #pragma unroll
                    for (int nf=0; nf<4; nf++)
                        racc[mf][nf] = __builtin_amdgcn_mfma_f32_16x16x32_bf16(af[mf], bf[nf], racc[mf][nf], 0,0,0);
            }
            #pragma unroll
            for (int mf=0; mf<4; mf++){
                #pragma unroll
                for (int nf=0; nf<4; nf++){
                    const int jj = wn*64 + nf*16 + l16;
                    #pragma unroll
                    for (int r=0;r<4;r++){
                        const int i = wm*64 + mf*16 + q4*4 + r;
                        Rb[pbase + (size_t)i*NCC + jj] = racc[mf][nf][r];
                    }
                }
            }
        }
    }
}

// ---------------- Phase B: S <- S*P + R over chunks; rows independent ----------------
__global__ __launch_bounds__(256) void k_phaseB(
    const __bf16* __restrict__ PTb, const float* __restrict__ Rb, float* __restrict__ Sb)
{
    __shared__ __attribute__((aligned(16))) float Ssh[16*132];
    const int tid = threadIdx.x;
    const int b = blockIdx.x >> 3, rb = blockIdx.x & 7;
    const int r0 = rb*16;
    const int lane = tid & 63, w = tid >> 6;
    const int q4 = lane >> 4, l16 = lane & 15;
    for (int i=tid; i<16*132; i+=256) Ssh[i] = 0.f;
    __syncthreads();
    for (int c=0; c<NCHUNK; c++){
        const size_t pbase = ((size_t)(b*NCHUNK + c))*NCC*NCC;
        {
            const int row = tid >> 4, cg = (tid & 15)*8;
            float* dst = Sb + pbase + (size_t)(r0+row)*NCC + cg;
            *(float4*)(dst)   = *(const float4*)(&Ssh[row*132+cg]);
            *(float4*)(dst+4) = *(const float4*)(&Ssh[row*132+cg+4]);
        }
        if (c == NCHUNK-1) break;
        v8bf af[4];
        #pragma unroll
        for (int ks=0; ks<4; ks++){
            const float* sr = &Ssh[l16*132 + ks*32 + q4*8];
            v8bf t;
            #pragma unroll
            for (int j=0;j<8;j++) t[j] = (__bf16)sr[j];
            af[ks] = t;
        }
        __syncthreads();
        v4f acc[2] = {};
        #pragma unroll
        for (int nt=0; nt<2; nt++){
            const int n0 = w*32 + nt*16;
            #pragma unroll
            for (int ks=0; ks<4; ks++){
                v8bf bf = *(const v8bf*)(PTb + pbase + (size_t)(n0+l16)*NCC + ks*32 + q4*8);
                acc[nt] = __builtin_amdgcn_mfma_f32_16x16x32_bf16(af[ks], bf, acc[nt], 0,0,0);
            }
        }
        #pragma unroll
        for (int nt=0; nt<2; nt++){
            const int n = w*32 + nt*16 + l16;
            #pragma unroll
            for (int r=0;r<4;r++){
                const int rowl = q4*4 + r;
                Ssh[rowl*132 + n] = acc[nt][r] + Rb[pbase + (size_t)(r0+rowl)*NCC + n];
            }
        }
        __syncthreads();
    }
}

// ---------------- Phase C: per-chunk outputs ----------------
__global__ __launch_bounds__(256) void k_phaseC(
    const float* __restrict__ qb, const float* __restrict__ kb,
    const float* __restrict__ Ub, const __bf16* __restrict__ Mb,
    const float* __restrict__ Sb, const float* __restrict__ lgb,
    float* __restrict__ gb)
{
    __shared__ __attribute__((aligned(16))) float S0T[NCC*132];
    __shared__ __attribute__((aligned(16))) __bf16 Msh[LCH*136];
    __shared__ __attribute__((aligned(16))) __bf16 Qsh[LCH*136];
    __shared__ __attribute__((aligned(16))) __bf16 Ksh[LCH*136];
    __shared__ __attribute__((aligned(16))) __bf16 Wsh[LCH*136];
    __shared__ __attribute__((aligned(16))) float Ash[LCH*68];
    __shared__ float lgs[LCH];

    const int tid = threadIdx.x;
    const int b = blockIdx.x >> 6, c = blockIdx.x & 63;
    const size_t base = (size_t)b*NT + (size_t)c*LCH;
    const size_t pbase = ((size_t)(b*NCHUNK + c))*NCC*NCC;

    {
        const int i = tid >> 1, j0 = (tid & 1)*64;
        const float* src = Sb + pbase + (size_t)i*NCC + j0;
        #pragma unroll 4
        for (int j=0;j<64;j+=4){
            float4 v = *(const float4*)(src+j);
            S0T[(j0+j  )*132 + i] = v.x;
            S0T[(j0+j+1)*132 + i] = v.y;
            S0T[(j0+j+2)*132 + i] = v.z;
            S0T[(j0+j+3)*132 + i] = v.w;
        }
    }
    {
        const int row = tid >> 2, seg = tid & 3;
        const __bf16* ms = Mb + (base+row)*NCC + seg*32;
        const float* qs = qb + (base+row)*NCC + seg*32;
        const float* ks = kb + (base+row)*NCC + seg*32;
        *(v8bf*)(&Msh[row*136+seg*32])    = *(const v8bf*)(ms);
        *(v8bf*)(&Msh[row*136+seg*32+8])  = *(const v8bf*)(ms+8);
        *(v8bf*)(&Msh[row*136+seg*32+16]) = *(const v8bf*)(ms+16);
        *(v8bf*)(&Msh[row*136+seg*32+24]) = *(const v8bf*)(ms+24);
        #pragma unroll 8
        for (int i=0;i<32;i++){
            Qsh[row*136+seg*32+i] = (__bf16)qs[i];
            Ksh[row*136+seg*32+i] = (__bf16)ks[i];
        }
    }
    if (tid < LCH) lgs[tid] = lgb[base+tid];
    __syncthreads();

    // X1 = M S0^T ; W = U - X1  -> Wsh
    {
        const int tg = tid >> 5, ig = tid & 31;
        float acc[8][4] = {};
        for (int j=0;j<NCC;j++){
            float m8[8];
            #pragma unroll
            for (int r=0;r<8;r++) m8[r] = (float)Msh[(tg*8+r)*136 + j];
            float4 sv = *(const float4*)(&S0T[j*132 + ig*4]);
            #pragma unroll
            for (int r=0;r<8;r++){
                acc[r][0] += m8[r]*sv.x; acc[r][1] += m8[r]*sv.y;
                acc[r][2] += m8[r]*sv.z; acc[r][3] += m8[r]*sv.w;
            }
        }
        #pragma unroll
        for (int r=0;r<8;r++){
            const int t = tg*8+r;
            const float4 uv = *(const float4*)(Ub + (base+t)*NCC + ig*4);
            Wsh[t*136+ig*4+0] = (__bf16)(uv.x - acc[r][0]);
            Wsh[t*136+ig*4+1] = (__bf16)(uv.y - acc[r][1]);
            Wsh[t*136+ig*4+2] = (__bf16)(uv.z - acc[r][2]);
            Wsh[t*136+ig*4+3] = (__bf16)(uv.w - acc[r][3]);
        }
    }
    // O2 = diag(gamma) Q S0 (kept in registers)
    float o2[8][4];
    {
        const int tg = tid >> 5, jg = tid & 31;
        float acc[8][4] = {};
        for (int i=0;i<NCC;i++){
            float q8[8];
            #pragma unroll
            for (int r=0;r<8;r++) q8[r] = (float)Qsh[(tg*8+r)*136 + i];
            float s4[4];
            #pragma unroll
            for (int rr=0;rr<4;rr++) s4[rr] = S0T[(jg+32*rr)*132 + i];
            #pragma unroll
            for (int r=0;r<8;r++){
                acc[r][0] += q8[r]*s4[0]; acc[r][1] += q8[r]*s4[1];
                acc[r][2] += q8[r]*s4[2]; acc[r][3] += q8[r]*s4[3];
            }
        }
        #pragma unroll
        for (int r=0;r<8;r++){
            const float g = __expf(lgs[tg*8+r]);
            #pragma unroll
            for (int d=0;d<4;d++) o2[r][d] = g*acc[r][d];
        }
    }
    __syncthreads();
    // X2 = Q W^T -> A = tril_incl(scaled)
    {
        const int tg2 = tid >> 4, sg = tid & 15;
        float acc[4][4] = {};
        for (int i=0;i<NCC;i++){
            float qv[4], wv[4];
            #pragma unroll
            for (int r=0;r<4;r++){
                qv[r] = (float)Qsh[(tg2+16*r)*136 + i];
                wv[r] = (float)Wsh[(sg+16*r)*136 + i];
            }
            #pragma unroll
            for (int a2=0;a2<4;a2++){
                acc[a2][0] += qv[a2]*wv[0]; acc[a2][1] += qv[a2]*wv[1];
                acc[a2][2] += qv[a2]*wv[2]; acc[a2][3] += qv[a2]*wv[3];
            }
        }
        #pragma unroll
        for (int a2=0;a2<4;a2++){
            const int t = tg2 + 16*a2;
            #pragma unroll
            for (int b2=0;b2<4;b2++){
                const int s = sg + 16*b2;
                Ash[t*68+s] = (s <= t) ? __expf(lgs[t]-lgs[s])*acc[a2][b2] : 0.f;
            }
        }
    }
    __syncthreads();
    // O1 = A K ; o = (O1 + O2) * gate  -> gb (in place)
    {
        const int tg = tid >> 5, jg = tid & 31;
        float acc[8][4] = {};
        for (int s=0;s<LCH;s++){
            float a8[8];
            #pragma unroll
            for (int r=0;r<8;r++) a8[r] = Ash[(tg*8+r)*68 + s];
            float k4[4];
            #pragma unroll
            for (int rr=0;rr<4;rr++) k4[rr] = (float)Ksh[s*136 + jg + 32*rr];
            #pragma unroll
            for (int r=0;r<8;r++){
                acc[r][0] += a8[r]*k4[0]; acc[r][1] += a8[r]*k4[1];
                acc[r][2] += a8[r]*k4[2]; acc[r][3] += a8[r]*k4[3];
            }
        }
        #pragma unroll
        for (int r=0;r<8;r++){
            const int t = tg*8+r;
            #pragma unroll
            for (int d=0;d<4;d++){
                const int j = jg + 32*d;
                const size_t off = (base+t)*NCC + j;
                gb[off] = (acc[r][d] + o2[r][d]) * gb[off];
            }
        }
    }
}

// ---------------- GEMM2: out = obar @ Wo^T + bo ----------------
__global__ __launch_bounds__(256) void k_out(
    const float* __restrict__ ob, const float* __restrict__ Wo,
    const float* __restrict__ bo, float* __restrict__ out)
{
    __shared__ __attribute__((aligned(16))) __bf16 As[128*40];
    __shared__ __attribute__((aligned(16))) __bf16 Bs[64*40];
    const int tid = threadIdx.x;
    const int m0 = blockIdx.x*128, n0 = blockIdx.y*64;
    const int lane = tid & 63, w = tid >> 6;
    const int q4 = lane >> 4, l16 = lane & 15;
    const int arow = tid >> 1, aseg = tid & 1;
    const int brow = tid >> 2, bseg = tid & 3;
    const float* asrc = ob + (size_t)(m0+arow)*NCC;
    const float* bsrc = Wo + (size_t)(n0+brow)*NCC;

    v4f acc[2][4] = {};

    for (int k0=0; k0<NCC; k0+=32){
        __syncthreads();
        {
            float4 f0 = *(const float4*)(asrc + k0 + aseg*16);
            float4 f1 = *(const float4*)(asrc + k0 + aseg*16 + 4);
            float4 f2 = *(const float4*)(asrc + k0 + aseg*16 + 8);
            float4 f3 = *(const float4*)(asrc + k0 + aseg*16 + 12);
            *(v8bf*)(&As[arow*40 + aseg*16])     = pack8(f0,f1);
            *(v8bf*)(&As[arow*40 + aseg*16 + 8]) = pack8(f2,f3);
        }
        {
            float4 g0 = *(const float4*)(bsrc + k0 + bseg*8);
            float4 g1 = *(const float4*)(bsrc + k0 + bseg*8 + 4);
            *(v8bf*)(&Bs[brow*40 + bseg*8]) = pack8(g0,g1);
        }
        __syncthreads();
        v8bf af0 = *(const v8bf*)(&As[(w*32 + l16)*40 + q4*8]);
        v8bf af1 = *(const v8bf*)(&As[(w*32 + 16 + l16)*40 + q4*8]);
        #pragma unroll
        for (int nt=0; nt<4; nt++){
            v8bf bf = *(const v8bf*)(&Bs[(nt*16 + l16)*40 + q4*8]);
            acc[0][nt] = __builtin_amdgcn_mfma_f32_16x16x32_bf16(af0, bf, acc[0][nt], 0,0,0);
            acc[1][nt] = __builtin_amdgcn_mfma_f32_16x16x32_bf16(af1, bf, acc[1][nt], 0,0,0);
        }
    }
    #pragma unroll
    for (int mt=0; mt<2; mt++){
        #pragma unroll
        for (int nt=0; nt<4; nt++){
            const int n = n0 + nt*16 + l16;
            const float bias = bo[n];
            #pragma unroll
            for (int r=0;r<4;r++){
                const int m = m0 + w*32 + mt*16 + q4*4 + r;
                out[(size_t)m*ND + n] = acc[mt][nt][r] + bias;
            }
        }
    }
}

extern "C" void kernel_launch(void* const* d_in, const int* in_sizes, int n_in,
                              void* d_out, int out_size, void* d_ws, size_t ws_size,
                              hipStream_t stream)
{
    const float* x  = (const float*)d_in[0];
    const float* Wq = (const float*)d_in[1];
    const float* bq = (const float*)d_in[2];
    const float* Wk = (const float*)d_in[3];
    const float* bk = (const float*)d_in[4];
    const float* Wv = (const float*)d_in[5];
    const float* bv = (const float*)d_in[6];
    const float* Wa = (const float*)d_in[7];
    const float* ba = (const float*)d_in[8];
    const float* Wb = (const float*)d_in[9];
    const float* bb2= (const float*)d_in[10];
    const float* Wg = (const float*)d_in[11];
    const float* bg = (const float*)d_in[12];
    const float* Wo = (const float*)d_in[13];
    const float* bo = (const float*)d_in[14];

    char* ws = (char*)d_ws;
    const size_t SZ = (size_t)BTROWS*NCC*4;     // 33.55 MB
    float*  qb  = (float*)(ws + 0*SZ);
    float*  kb  = (float*)(ws + 1*SZ);
    float*  vb  = (float*)(ws + 2*SZ);          // v, overwritten by U
    __bf16* Mb  = (__bf16*)(ws + 3*SZ);         // bf16 M (half of slot used)
    float*  gb  = (float*)(ws + 4*SZ);          // gate, overwritten by obar
    float*  Sb  = (float*)(ws + 5*SZ);          // 2*SZ: per-chunk incoming states
    float*  Rb  = (float*)(ws + 7*SZ);          // 2*SZ
    __bf16* PTb = (__bf16*)(ws + 9*SZ);         // SZ bytes (bf16)
    float*  ab  = (float*)(ws + 10*SZ);
    float*  beb = (float*)(ws + 10*SZ + 262144);
    float*  lgb = (float*)(ws + 10*SZ + 524288);
    // transient (pre-phaseA) reuse of Sb/Rb/PTb region:
    __bf16* xbf = (__bf16*)(ws + 5*SZ);         // 4*SZ bytes (65536x1024 bf16) = slots 5..9
    __bf16* wbf = (__bf16*)(ws + 9*SZ);         // 1 MB (512x1024 bf16), freed before phaseA writes PTb
    if (ws_size < 10*SZ + 786432) return;       // insufficient workspace

    dim3 blk(256);
    k_wcast <<<dim3(128),            blk, 0, stream>>>(Wq,Wk,Wv,Wg,wbf);
    k_xcast <<<dim3(BTROWS/4),       blk, 0, stream>>>(x,Wa,Wb,ba,bb2,xbf,ab,beb);
    k_proj2 <<<dim3(2048),           blk, 0, stream>>>(xbf,wbf,bq,bk,bv,bg,qb,kb,vb,gb);
    k_knorm <<<dim3(BTROWS/4),       blk, 0, stream>>>(kb);
    k_phaseA<<<dim3(NB*NCHUNK),      blk, 0, stream>>>(kb, vb, Mb, ab, beb, lgb, PTb, Rb);
    k_phaseB<<<dim3(NB*8),           blk, 0, stream>>>(PTb, Rb, Sb);
    k_phaseC<<<dim3(NB*NCHUNK),      blk, 0, stream>>>(qb, kb, vb, Mb, Sb, lgb, gb);
    k_out   <<<dim3(BTROWS/128, 16), blk, 0, stream>>>(gb, Wo, bo, (float*)d_out);
}

// Round 3
// 1073.197 us; speedup vs baseline: 1.4643x; 1.1256x over previous
//
#include <hip/hip_runtime.h>
#include <hip/hip_bf16.h>
#include <math.h>

#define NB 16
#define NT 4096
#define ND 1024
#define NCC 128
#define LCH 64
#define NCHUNK 64
#define BTROWS 65536

typedef __bf16 v8bf __attribute__((ext_vector_type(8)));
typedef float  v4f  __attribute__((ext_vector_type(4)));

static __device__ __forceinline__ float sig_(float x){ return 1.0f/(1.0f + __expf(-x)); }
static __device__ __forceinline__ float dot4_(float4 a, float4 b){
    return a.x*b.x + a.y*b.y + a.z*b.z + a.w*b.w;
}

static __device__ __forceinline__ v8bf pack8(float4 a, float4 b){
    v8bf v;
    v[0]=(__bf16)a.x; v[1]=(__bf16)a.y; v[2]=(__bf16)a.z; v[3]=(__bf16)a.w;
    v[4]=(__bf16)b.x; v[5]=(__bf16)b.y; v[6]=(__bf16)b.z; v[7]=(__bf16)b.w;
    return v;
}

// async global->LDS, 16B per lane; lds dst is wave-uniform base (+lane*16 by HW)
static __device__ __forceinline__ void gload16(const void* g, void* l){
    __builtin_amdgcn_global_load_lds(
        (const __attribute__((address_space(1))) unsigned int*)g,
        (__attribute__((address_space(3))) unsigned int*)l, 16, 0, 0);
}

// ---------------- x -> bf16, fused alpha/beta GEMV ----------------
__global__ __launch_bounds__(256) void k_xcast(
    const float* __restrict__ x, const float* __restrict__ Wa,
    const float* __restrict__ Wb, const float* __restrict__ ba,
    const float* __restrict__ bb2, __bf16* __restrict__ xbf,
    float* __restrict__ ab, float* __restrict__ beb)
{
    const int tid = threadIdx.x;
    const int w = tid >> 6, lane = tid & 63;
    const size_t row = (size_t)blockIdx.x*4 + w;
    const float* xr = x + row*ND + lane*16;
    float4 f0 = ((const float4*)xr)[0];
    float4 f1 = ((const float4*)xr)[1];
    float4 f2 = ((const float4*)xr)[2];
    float4 f3 = ((const float4*)xr)[3];
    const float4* wa = (const float4*)(Wa + lane*16);
    const float4* wb = (const float4*)(Wb + lane*16);
    float da = dot4_(f0,wa[0]) + dot4_(f1,wa[1]) + dot4_(f2,wa[2]) + dot4_(f3,wa[3]);
    float db = dot4_(f0,wb[0]) + dot4_(f1,wb[1]) + dot4_(f2,wb[2]) + dot4_(f3,wb[3]);
    __bf16* xd = xbf + row*ND + lane*16;
    *(v8bf*)(xd)   = pack8(f0,f1);
    *(v8bf*)(xd+8) = pack8(f2,f3);
    #pragma unroll
    for (int m=1;m<64;m<<=1){ da += __shfl_xor(da,m,64); db += __shfl_xor(db,m,64); }
    if (lane == 0){
        ab[row]  = sig_(da + ba[0]);
        beb[row] = sig_(db + bb2[0]);
    }
}

// ---------------- W concat -> bf16 ----------------
__global__ __launch_bounds__(256) void k_wcast(
    const float* __restrict__ Wq, const float* __restrict__ Wk,
    const float* __restrict__ Wv, const float* __restrict__ Wg,
    __bf16* __restrict__ wbf)
{
    const int tid = threadIdx.x;
    const int w = tid >> 6, lane = tid & 63;
    const int row = blockIdx.x*4 + w;     // 0..511
    const float* src = (row < 128) ? Wq + (size_t)row*ND
                     : (row < 256) ? Wk + (size_t)(row-128)*ND
                     : (row < 384) ? Wv + (size_t)(row-256)*ND
                     :               Wg + (size_t)(row-384)*ND;
    const float4* s4 = (const float4*)(src + lane*16);
    float4 f0=s4[0], f1=s4[1], f2=s4[2], f3=s4[3];
    __bf16* xd = wbf + (size_t)row*ND + lane*16;
    *(v8bf*)(xd)   = pack8(f0,f1);
    *(v8bf*)(xd+8) = pack8(f2,f3);
}

// ---------------- GEMM1: [q k v g] = x_bf @ W_bf^T (m97 structure) ----------------
__global__ __launch_bounds__(256) void k_proj2(
    const __bf16* __restrict__ xbf, const __bf16* __restrict__ wbf,
    const float* __restrict__ bq, const float* __restrict__ bk,
    const float* __restrict__ bv, const float* __restrict__ bg,
    float* __restrict__ qb, float* __restrict__ kb2,
    float* __restrict__ vb, float* __restrict__ gb)
{
    __shared__ __attribute__((aligned(16))) __bf16 As[128*64];
    __shared__ __attribute__((aligned(16))) __bf16 Bs[128*64];
    const int tid = threadIdx.x;
    const int lane = tid & 63, w = tid >> 6;
    const int q4 = lane >> 4, l16 = lane & 15;
    const int wm = w >> 1, wn = w & 1;

    const int f = blockIdx.x;
    const int xcd = f & 7, j = f >> 3;
    const int m0 = ((xcd << 6) + (j >> 2)) * 128;
    const int n0 = (j & 3) * 128;

    v4f acc[4][4] = {};

    for (int k0 = 0; k0 < ND; k0 += 64){
        __syncthreads();
        #pragma unroll
        for (int i=0;i<4;i++){
            const int r  = (w*4+i)*8 + (lane >> 3);
            const int ce = (((lane & 7) ^ (r & 7)) << 3);   // pre-swizzled source col (elems)
            gload16(xbf + (size_t)(m0 + r)*ND + k0 + ce, (char*)As + (w*4+i)*1024);
            gload16(wbf + (size_t)(n0 + r)*ND + k0 + ce, (char*)Bs + (w*4+i)*1024);
        }
        __syncthreads();
        #pragma unroll
        for (int ks=0; ks<2; ks++){
            v8bf af[4], bf[4];
            #pragma unroll
            for (int mf=0; mf<4; mf++){
                const int r = wm*64 + mf*16 + l16;
                af[mf] = *(const v8bf*)((const char*)As + r*128 + (((ks*4+q4) ^ (r&7)) << 4));
            }
            #pragma unroll
            for (int nf=0; nf<4; nf++){
                const int r = wn*64 + nf*16 + l16;
                bf[nf] = *(const v8bf*)((const char*)Bs + r*128 + (((ks*4+q4) ^ (r&7)) << 4));
            }
            #pragma unroll
            for (int mf=0; mf<4; mf++)
                #pragma unroll
                for (int nf=0; nf<4; nf++)
                    acc[mf][nf] = __builtin_amdgcn_mfma_f32_16x16x32_bf16(af[mf], bf[nf], acc[mf][nf], 0,0,0);
        }
    }

    #pragma unroll
    for (int mf=0; mf<4; mf++){
        #pragma unroll
        for (int nf=0; nf<4; nf++){
            const int ng  = n0 + wn*64 + nf*16 + l16;   // 0..511
            const int col = ng & 127;
            const int sel = ng >> 7;
            const float bias = (sel==0) ? bq[col] : (sel==1) ? bk[col]
                             : (sel==2) ? bv[col] : bg[col];
            #pragma unroll
            for (int r2=0;r2<4;r2++){
                const int m = m0 + wm*64 + mf*16 + q4*4 + r2;
                const float val = acc[mf][nf][r2] + bias;
                const size_t off = (size_t)m*NCC + col;
                if      (sel == 0) qb[off]  = val;
                else if (sel == 1) kb2[off] = val;
                else if (sel == 2) vb[off]  = val;
                else               gb[off]  = sig_(val);
            }
        }
    }
}

// ---------------- normalize k rows ----------------
__global__ __launch_bounds__(256) void k_knorm(float* __restrict__ kb){
    const int tid = threadIdx.x;
    const int w = tid >> 6, lane = tid & 63;
    const size_t row = (size_t)blockIdx.x*4 + w;
    float* kr = kb + row*NCC;
    float a = kr[lane], b = kr[lane+64];
    float ss = a*a + b*b;
    #pragma unroll
    for (int m=1;m<64;m<<=1) ss += __shfl_xor(ss, m, 64);
    float inv = 1.0f / fmaxf(sqrtf(ss), 1e-12f);
    kr[lane] = a*inv; kr[lane+64] = b*inv;
}

// ---------------- Phase A: per-chunk precompute ----------------
#define KSWZ(t, j)   ((t)*132 + ((((((j)>>2) ^ ((t)&7))) << 2) | ((j)&3)))
#define KSWZ4(t, j4) ((t)*132 + ((((j4) ^ ((t)&7))) << 2))
#define TSWZ(row, g) ((row)*72 + ((((g) ^ ((row)&7))) << 3))

#define SOLVE_LOOP(RHS_EXPR) \
    _Pragma("unroll") \
    for (int t=0;t<64;t++){ \
        const float* Gr = &Gsh[t*68]; \
        float s0=0.f,s1=0.f,s2=0.f,s3=0.f; \
        _Pragma("unroll") \
        for (int s4=0; s4+4<=t; s4+=4){ \
            float4 g = *(const float4*)(Gr+s4); \
            s0 += g.x*u[s4]; s1 += g.y*u[s4+1]; s2 += g.z*u[s4+2]; s3 += g.w*u[s4+3]; \
        } \
        _Pragma("unroll") \
        for (int s=(t & ~3); s<t; s++) s0 += Gr[s]*u[s]; \
        u[t] = bsh[t]*((RHS_EXPR) - ((s0+s1)+(s2+s3))); \
    }

__global__ __launch_bounds__(256) void k_phaseA(
    const float* __restrict__ kb, float* __restrict__ vb, __bf16* __restrict__ Mb,
    const float* __restrict__ ab, const float* __restrict__ beb,
    float* __restrict__ lgb, __bf16* __restrict__ PTb, float* __restrict__ Rb)
{
    __shared__ __attribute__((aligned(16))) float Ksh[LCH*132];   // swizzled (KSWZ)
    __shared__ __attribute__((aligned(16))) float Vsh[LCH*132];   // linear
    __shared__ __attribute__((aligned(16))) float Gsh[LCH*68];
    __shared__ __attribute__((aligned(16))) __bf16 KT [NCC*72];   // KT[j][t], swz TSWZ
    __shared__ __attribute__((aligned(16))) __bf16 EUT[NCC*72];   // e_t*u_t[i]
    __shared__ __attribute__((aligned(16))) __bf16 EMT[NCC*72];   // e_t*m_t[m]
    __shared__ float lgs[LCH], bsh[LCH], esh[LCH], gam[LCH];

    const int tid = threadIdx.x;
    const int b = blockIdx.x >> 6;
    const int c = blockIdx.x & 63;
    const size_t base = (size_t)b*NT + (size_t)c*LCH;

    if (tid < LCH){
        float la = __logf(fmaxf(ab[base+tid], 1e-30f));
        float ps = la;
        #pragma unroll
        for (int off=1; off<64; off<<=1){
            float o = __shfl_up(ps, off, 64);
            if ((tid & 63) >= off) ps += o;
        }
        lgs[tid] = ps;
        bsh[tid] = beb[base+tid];
    }
    // stage K (swizzled) and V (linear)
    {
        const int row = tid >> 2, seg = tid & 3;
        const float* ks = kb + (base+row)*NCC + seg*32;
        const float* vs = vb + (base+row)*NCC + seg*32;
        #pragma unroll
        for (int i=0;i<32;i+=4){
            float4 kv = *(const float4*)(ks+i);
            float4 vv = *(const float4*)(vs+i);
            *(float4*)(&Ksh[KSWZ4(row, ((seg*32+i)>>2))]) = kv;
            *(float4*)(&Vsh[row*132 + seg*32 + i]) = vv;
        }
    }
    __syncthreads();
    if (tid < LCH){
        lgb[base+tid] = lgs[tid];
        esh[tid] = __expf(lgs[LCH-1] - lgs[tid]);
        gam[tid] = __expf(lgs[tid]);
    }
    // G[t][s] = exp(lg_t - lg_s) * (k_s . k_t), s <= t
    for (int idx = tid; idx < (LCH*(LCH+1))/2; idx += 256){
        int t = (int)((sqrtf(8.f*(float)idx + 1.f) - 1.f)*0.5f);
        while ((t+1)*(t+2)/2 <= idx) t++;
        while (t*(t+1)/2 > idx) t--;
        const int s = idx - (t*(t+1))/2;
        float dot = 0.f;
        #pragma unroll 8
        for (int j4=0;j4<32;j4++){
            float4 u = *(const float4*)(&Ksh[KSWZ4(s,j4)]);
            float4 v = *(const float4*)(&Ksh[KSWZ4(t,j4)]);
            dot += u.x*v.x + u.y*v.y + u.z*v.z + u.w*v.w;
        }
        Gsh[t*68+s] = __expf(lgs[t]-lgs[s])*dot;
    }
    // KT[j][t] = bf16(k_t[j])  (transposed, swizzled rows)
    {
        const int j = tid & 127, th = tid >> 7;
        #pragma unroll
        for (int g=0; g<4; g++){
            const int t0 = th*32 + g*8;
            v8bf pk;
            #pragma unroll
            for (int e=0;e<8;e++) pk[e] = (__bf16)Ksh[KSWZ(t0+e, j)];
            *(v8bf*)(&KT[TSWZ(j, (t0>>3))]) = pk;
        }
    }
    __syncthreads();

    // barrier-free forward substitution; column lives in registers
    {
        const int half = tid >> 7, cix = tid & 127;
        float u[64];
        if (half == 0){
            SOLVE_LOOP(Vsh[t*132 + cix])
            #pragma unroll
            for (int t=0;t<64;t++) vb[(base+t)*NCC + cix] = u[t];   // U over v
            #pragma unroll
            for (int g=0; g<8; g++){
                v8bf pk;
                #pragma unroll
                for (int e=0;e<8;e++) pk[e] = (__bf16)(esh[g*8+e]*u[g*8+e]);
                *(v8bf*)(&EUT[TSWZ(cix, g)]) = pk;
            }
        } else {
            SOLVE_LOOP(gam[t]*Ksh[KSWZ(t, cix)])
            #pragma unroll
            for (int t=0;t<64;t++) Mb[(base+t)*NCC + cix] = (__bf16)u[t];
            #pragma unroll
            for (int g=0; g<8; g++){
                v8bf pk;
                #pragma unroll
                for (int e=0;e<8;e++) pk[e] = (__bf16)(esh[g*8+e]*u[g*8+e]);
                *(v8bf*)(&EMT[TSWZ(cix, g)]) = pk;
            }
        }
    }
    __syncthreads();

    // MFMA: P^T[j][m] = gl*delta - sum_t KT[j][t]*EMT[m][t]
    //       R  [i][j] =            sum_t EUT[i][t]*KT [j][t]
    {
        const int lane = tid & 63, w = tid >> 6;
        const int q4 = lane >> 4, l16 = lane & 15;
        const int wm = w >> 1, wn = w & 1;
        const float gl = gam[LCH-1];
        const size_t pbase = ((size_t)(b*NCHUNK + c))*NCC*NCC;
        {
            v4f pacc[4][4] = {};
            #pragma unroll
            for (int ks=0; ks<2; ks++){
                v8bf af[4], bf[4];
                #pragma unroll
                for (int mf=0; mf<4; mf++)
                    af[mf] = *(const v8bf*)(&KT[TSWZ(wm*64+mf*16+l16, ks*4+q4)]);
                #pragma unroll
                for (int nf=0; nf<4; nf++)
                    bf[nf] = *(const v8bf*)(&EMT[TSWZ(wn*64+nf*16+l16, ks*4+q4)]);
                #pragma unroll
                for (int mf=0; mf<4; mf++)
                    #pragma unroll
                    for (int nf=0; nf<4; nf++)
                        pacc[mf][nf] = __builtin_amdgcn_mfma_f32_16x16x32_bf16(af[mf], bf[nf], pacc[mf][nf], 0,0,0);
            }
            #pragma unroll
            for (int mf=0; mf<4; mf++){
                #pragma unroll
                for (int nf=0; nf<4; nf++){
                    const int m = wn*64 + nf*16 + l16;
                    #pragma unroll
                    for (int r=0;r<4;r++){
                        const int j = wm*64 + mf*16 + q4*4 + r;
                        float v = -pacc[mf][nf][r];
                        if (j == m) v += gl;
                        PTb[pbase + (size_t)j*NCC + m] = (__bf16)v;
                    }
                }
            }
        }
        {
            v4f racc[4][4] = {};
            #pragma unroll
            for (int ks=0; ks<2; ks++){
                v8bf af[4], bf[4];
                #pragma unroll
                for (int mf=0; mf<4; mf++)
                    af[mf] = *(const v8bf*)(&EUT[TSWZ(wm*64+mf*16+l16, ks*4+q4)]);
                #pragma unroll
                for (int nf=0; nf<4; nf++)
                    bf[nf] = *(const v8bf*)(&KT[TSWZ(wn*64+nf*16+l16, ks*4+q4)]);
                #pragma unroll
                for (int mf=0; mf<4; mf++)
                    #pragma unroll
                    for (int nf=0; nf<4; nf++)
                        racc[mf][nf] = __builtin_amdgcn_mfma_f32_16x16x32_bf16(af[mf], bf[nf], racc[mf][nf], 0,0,0);
            }
            #pragma unroll
            for (int mf=0; mf<4; mf++){
                #pragma unroll
                for (int nf=0; nf<4; nf++){
                    const int jj = wn*64 + nf*16 + l16;
                    #pragma unroll
                    for (int r=0;r<4;r++){
                        const int i = wm*64 + mf*16 + q4*4 + r;
                        Rb[pbase + (size_t)i*NCC + jj] = racc[mf][nf][r];
                    }
                }
            }
        }
    }
}

// ---------------- Phase B: S <- S*P + R over chunks; rows independent ----------------
__global__ __launch_bounds__(256) void k_phaseB(
    const __bf16* __restrict__ PTb, const float* __restrict__ Rb, float* __restrict__ Sb)
{
    __shared__ __attribute__((aligned(16))) float Ssh[16*132];
    const int tid = threadIdx.x;
    const int b = blockIdx.x >> 3, rb = blockIdx.x & 7;
    const int r0 = rb*16;
    const int lane = tid & 63, w = tid >> 6;
    const int q4 = lane >> 4, l16 = lane & 15;
    for (int i=tid; i<16*132; i+=256) Ssh[i] = 0.f;
    __syncthreads();
    for (int c=0; c<NCHUNK; c++){
        const size_t pbase = ((size_t)(b*NCHUNK + c))*NCC*NCC;
        {
            const int row = tid >> 4, cg = (tid & 15)*8;
            float* dst = Sb + pbase + (size_t)(r0+row)*NCC + cg;
            *(float4*)(dst)   = *(const float4*)(&Ssh[row*132+cg]);
            *(float4*)(dst+4) = *(const float4*)(&Ssh[row*132+cg+4]);
        }
        if (c == NCHUNK-1) break;
        v8bf af[4];
        #pragma unroll
        for (int ks=0; ks<4; ks++){
            const float* sr = &Ssh[l16*132 + ks*32 + q4*8];
            v8bf t;
            #pragma unroll
            for (int j=0;j<8;j++) t[j] = (__bf16)sr[j];
            af[ks] = t;
        }
        __syncthreads();
        v4f acc[2] = {};
        #pragma unroll
        for (int nt=0; nt<2; nt++){
            const int n0 = w*32 + nt*16;
            #pragma unroll
            for (int ks=0; ks<4; ks++){
                v8bf bf = *(const v8bf*)(PTb + pbase + (size_t)(n0+l16)*NCC + ks*32 + q4*8);
                acc[nt] = __builtin_amdgcn_mfma_f32_16x16x32_bf16(af[ks], bf, acc[nt], 0,0,0);
            }
        }
        #pragma unroll
        for (int nt=0; nt<2; nt++){
            const int n = w*32 + nt*16 + l16;
            #pragma unroll
            for (int r=0;r<4;r++){
                const int rowl = q4*4 + r;
                Ssh[rowl*132 + n] = acc[nt][r] + Rb[pbase + (size_t)(r0+rowl)*NCC + n];
            }
        }
        __syncthreads();
    }
}

// ---------------- Phase C: per-chunk outputs (MFMA) ----------------
__global__ __launch_bounds__(256) void k_phaseC(
    const float* __restrict__ qb, const float* __restrict__ kb,
    const float* __restrict__ Ub, const __bf16* __restrict__ Mb,
    const float* __restrict__ Sb, const float* __restrict__ lgb,
    float* __restrict__ gb)
{
    __shared__ __attribute__((aligned(16))) __bf16 S0r[NCC*136];  // S0 rows (bf16)
    __shared__ __attribute__((aligned(16))) __bf16 S0t[NCC*136];  // S0^T rows (bf16)
    __shared__ __attribute__((aligned(16))) __bf16 MA [LCH*136];  // Msh, then Ash (pitch 72, TSWZ)
    __shared__ __attribute__((aligned(16))) __bf16 Wsh[LCH*136];
    __shared__ __attribute__((aligned(16))) __bf16 KT [NCC*72];   // K^T[j][s], TSWZ
    __shared__ float lgs[LCH];

    const int tid = threadIdx.x;
    const int b = blockIdx.x >> 6, c = blockIdx.x & 63;
    const size_t base = (size_t)b*NT + (size_t)c*LCH;
    const size_t pbase = ((size_t)(b*NCHUNK + c))*NCC*NCC;
    const int lane = tid & 63, w = tid >> 6;
    const int q4 = lane >> 4, l16 = lane & 15;

    if (tid < LCH) lgs[tid] = lgb[base+tid];
    // S0 staging: bf16 rows + bf16 transpose
    {
        const int i = tid >> 1, jh = (tid & 1)*64;
        const float* src = Sb + pbase + (size_t)i*NCC + jh;
        #pragma unroll
        for (int g=0; g<8; g++){
            float4 a = *(const float4*)(src + g*8);
            float4 d = *(const float4*)(src + g*8 + 4);
            v8bf pk = pack8(a,d);
            *(v8bf*)(&S0r[i*136 + jh + g*8]) = pk;
            #pragma unroll
            for (int e=0;e<8;e++) S0t[(jh + g*8 + e)*136 + i] = pk[e];
        }
    }
    // M rows (bf16 global -> LDS, straight copy)
    {
        const int row = tid >> 2, seg = (tid & 3)*32;
        const __bf16* ms = Mb + (base+row)*NCC + seg;
        *(v8bf*)(&MA[row*136 + seg])      = *(const v8bf*)(ms);
        *(v8bf*)(&MA[row*136 + seg + 8])  = *(const v8bf*)(ms+8);
        *(v8bf*)(&MA[row*136 + seg + 16]) = *(const v8bf*)(ms+16);
        *(v8bf*)(&MA[row*136 + seg + 24]) = *(const v8bf*)(ms+24);
    }
    // K -> KT (transposed, TSWZ); coalesced row reads
    {
        const int j = tid & 127, th = tid >> 7;
        #pragma unroll
        for (int g=0; g<4; g++){
            const int sg = th*4 + g;
            const int s0 = sg*8;
            v8bf pk;
            #pragma unroll
            for (int e=0;e<8;e++) pk[e] = (__bf16)kb[(base+s0+e)*NCC + j];
            *(v8bf*)(&KT[TSWZ(j, sg)]) = pk;
        }
    }
    // Q fragments in registers (A-operand for O2 and X2; contraction over i)
    v8bf qf[4];
    #pragma unroll
    for (int ks=0; ks<4; ks++){
        const float* qs = qb + (base + w*16 + l16)*NCC + ks*32 + q4*8;
        float4 a = *(const float4*)(qs);
        float4 d = *(const float4*)(qs+4);
        qf[ks] = pack8(a,d);
    }
    __syncthreads();

    // X1 = M S0^T ; W = U - X1 -> Wsh
    {
        v4f x1[8] = {};
        #pragma unroll
        for (int ks=0; ks<4; ks++){
            v8bf af = *(const v8bf*)(&MA[(w*16+l16)*136 + ks*32 + q4*8]);
            #pragma unroll
            for (int ib=0; ib<8; ib++){
                v8bf bf = *(const v8bf*)(&S0r[(ib*16+l16)*136 + ks*32 + q4*8]);
                x1[ib] = __builtin_amdgcn_mfma_f32_16x16x32_bf16(af, bf, x1[ib], 0,0,0);
            }
        }
        #pragma unroll
        for (int ib=0; ib<8; ib++){
            #pragma unroll
            for (int r=0;r<4;r++){
                const int t = w*16 + q4*4 + r;
                const int i = ib*16 + l16;
                const float u = Ub[(base+t)*NCC + i];
                Wsh[t*136 + i] = (__bf16)(u - x1[ib][r]);
            }
        }
    }
    // O2 = Q S0 (registers; gamma applied at epilogue)
    v4f o2[8] = {};
    #pragma unroll
    for (int ks=0; ks<4; ks++){
        #pragma unroll
        for (int jb=0; jb<8; jb++){
            v8bf bf = *(const v8bf*)(&S0t[(jb*16+l16)*136 + ks*32 + q4*8]);
            o2[jb] = __builtin_amdgcn_mfma_f32_16x16x32_bf16(qf[ks], bf, o2[jb], 0,0,0);
        }
    }
    __syncthreads();   // Wsh ready; MA (Msh) reads complete -> can be overwritten as Ash

    // X2 = Q W^T -> A = tril_incl(exp(lg_t-lg_s) * X2), bf16, into MA (pitch 72, TSWZ)
    {
        v4f x2[4] = {};
        #pragma unroll
        for (int ks=0; ks<4; ks++){
            #pragma unroll
            for (int sb=0; sb<4; sb++){
                v8bf bf = *(const v8bf*)(&Wsh[(sb*16+l16)*136 + ks*32 + q4*8]);
                x2[sb] = __builtin_amdgcn_mfma_f32_16x16x32_bf16(qf[ks], bf, x2[sb], 0,0,0);
            }
        }
        #pragma unroll
        for (int sb=0; sb<4; sb++){
            #pragma unroll
            for (int r=0;r<4;r++){
                const int t = w*16 + q4*4 + r;
                const int s = sb*16 + l16;
                const float v = (s <= t) ? __expf(lgs[t]-lgs[s])*x2[sb][r] : 0.f;
                MA[t*72 + ((((s>>3) ^ (t&7))) << 3) + (s&7)] = (__bf16)v;
            }
        }
    }
    __syncthreads();   // Ash ready

    // O1 = A K ; o = (O1 + gamma*O2) * gate -> gb in place
    {
        v4f o1[8] = {};
        #pragma unroll
        for (int ks=0; ks<2; ks++){
            v8bf af = *(const v8bf*)(&MA[TSWZ(w*16+l16, ks*4+q4)]);
            #pragma unroll
            for (int jb=0; jb<8; jb++){
                v8bf bf = *(const v8bf*)(&KT[TSWZ(jb*16+l16, ks*4+q4)]);
                o1[jb] = __builtin_amdgcn_mfma_f32_16x16x32_bf16(af, bf, o1[jb], 0,0,0);
            }
        }
        float gam4[4];
        #pragma unroll
        for (int r=0;r<4;r++) gam4[r] = __expf(lgs[w*16 + q4*4 + r]);
        #pragma unroll
        for (int jb=0; jb<8; jb++){
            #pragma unroll
            for (int r=0;r<4;r++){
                const int t = w*16 + q4*4 + r;
                const int j = jb*16 + l16;
                const size_t off = (size_t)(base+t)*NCC + j;
                gb[off] = (o1[jb][r] + gam4[r]*o2[jb][r]) * gb[off];
            }
        }
    }
}

// ---------------- GEMM2: out = obar @ Wo^T + bo ----------------
__global__ __launch_bounds__(256) void k_out(
    const float* __restrict__ ob, const float* __restrict__ Wo,
    const float* __restrict__ bo, float* __restrict__ out)
{
    __shared__ __attribute__((aligned(16))) __bf16 As[128*40];
    __shared__ __attribute__((aligned(16))) __bf16 Bs[64*40];
    const int tid = threadIdx.x;
    const int m0 = blockIdx.x*128, n0 = blockIdx.y*64;
    const int lane = tid & 63, w = tid >> 6;
    const int q4 = lane >> 4, l16 = lane & 15;
    const int arow = tid >> 1, aseg = tid & 1;
    const int brow = tid >> 2, bseg = tid & 3;
    const float* asrc = ob + (size_t)(m0+arow)*NCC;
    const float* bsrc = Wo + (size_t)(n0+brow)*NCC;

    v4f acc[2][4] = {};

    for (int k0=0; k0<NCC; k0+=32){
        __syncthreads();
        {
            float4 f0 = *(const float4*)(asrc + k0 + aseg*16);
            float4 f1 = *(const float4*)(asrc + k0 + aseg*16 + 4);
            float4 f2 = *(const float4*)(asrc + k0 + aseg*16 + 8);
            float4 f3 = *(const float4*)(asrc + k0 + aseg*16 + 12);
            *(v8bf*)(&As[arow*40 + aseg*16])     = pack8(f0,f1);
            *(v8bf*)(&As[arow*40 + aseg*16 + 8]) = pack8(f2,f3);
        }
        {
            float4 g0 = *(const float4*)(bsrc + k0 + bseg*8);
            float4 g1 = *(const float4*)(bsrc + k0 + bseg*8 + 4);
            *(v8bf*)(&Bs[brow*40 + bseg*8]) = pack8(g0,g1);
        }
        __syncthreads();
        v8bf af0 = *(const v8bf*)(&As[(w*32 + l16)*40 + q4*8]);
        v8bf af1 = *(const v8bf*)(&As[(w*32 + 16 + l16)*40 + q4*8]);
        #pragma unroll
        for (int nt=0; nt<4; nt++){
            v8bf bf = *(const v8bf*)(&Bs[(nt*16 + l16)*40 + q4*8]);
            acc[0][nt] = __builtin_amdgcn_mfma_f32_16x16x32_bf16(af0, bf, acc[0][nt], 0,0,0);
            acc[1][nt] = __builtin_amdgcn_mfma_f32_16x16x32_bf16(af1, bf, acc[1][nt], 0,0,0);
        }
    }
    #pragma unroll
    for (int mt=0; mt<2; mt++){
        #pragma unroll
        for (int nt=0; nt<4; nt++){
            const int n = n0 + nt*16 + l16;
            const float bias = bo[n];
            #pragma unroll
            for (int r=0;r<4;r++){
                const int m = m0 + w*32 + mt*16 + q4*4 + r;
                out[(size_t)m*ND + n] = acc[mt][nt][r] + bias;
            }
        }
    }
}

extern "C" void kernel_launch(void* const* d_in, const int* in_sizes, int n_in,
                              void* d_out, int out_size, void* d_ws, size_t ws_size,
                              hipStream_t stream)
{
    const float* x  = (const float*)d_in[0];
    const float* Wq = (const float*)d_in[1];
    const float* bq = (const float*)d_in[2];
    const float* Wk = (const float*)d_in[3];
    const float* bk = (const float*)d_in[4];
    const float* Wv = (const float*)d_in[5];
    const float* bv = (const float*)d_in[6];
    const float* Wa = (const float*)d_in[7];
    const float* ba = (const float*)d_in[8];
    const float* Wb = (const float*)d_in[9];
    const float* bb2= (const float*)d_in[10];
    const float* Wg = (const float*)d_in[11];
    const float* bg = (const float*)d_in[12];
    const float* Wo = (const float*)d_in[13];
    const float* bo = (const float*)d_in[14];

    char* ws = (char*)d_ws;
    const size_t SZ = (size_t)BTROWS*NCC*4;     // 33.55 MB
    float*  qb  = (float*)(ws + 0*SZ);
    float*  kb  = (float*)(ws + 1*SZ);
    float*  vb  = (float*)(ws + 2*SZ);          // v, overwritten by U
    __bf16* Mb  = (__bf16*)(ws + 3*SZ);         // bf16 M (half of slot used)
    float*  gb  = (float*)(ws + 4*SZ);          // gate, overwritten by obar
    float*  Sb  = (float*)(ws + 5*SZ);          // 2*SZ: per-chunk incoming states
    float*  Rb  = (float*)(ws + 7*SZ);          // 2*SZ
    __bf16* PTb = (__bf16*)(ws + 9*SZ);         // SZ bytes (bf16)
    float*  ab  = (float*)(ws + 10*SZ);
    float*  beb = (float*)(ws + 10*SZ + 262144);
    float*  lgb = (float*)(ws + 10*SZ + 524288);
    // transient (pre-phaseA) reuse of Sb/Rb/PTb region:
    __bf16* xbf = (__bf16*)(ws + 5*SZ);         // 4*SZ bytes (65536x1024 bf16) = slots 5..9
    __bf16* wbf = (__bf16*)(ws + 9*SZ);         // 1 MB (512x1024 bf16), freed before phaseA writes PTb
    if (ws_size < 10*SZ + 786432) return;       // insufficient workspace

    dim3 blk(256);
    k_wcast <<<dim3(128),            blk, 0, stream>>>(Wq,Wk,Wv,Wg,wbf);
    k_xcast <<<dim3(BTROWS/4),       blk, 0, stream>>>(x,Wa,Wb,ba,bb2,xbf,ab,beb);
    k_proj2 <<<dim3(2048),           blk, 0, stream>>>(xbf,wbf,bq,bk,bv,bg,qb,kb,vb,gb);
    k_knorm <<<dim3(BTROWS/4),       blk, 0, stream>>>(kb);
    k_phaseA<<<dim3(NB*NCHUNK),      blk, 0, stream>>>(kb, vb, Mb, ab, beb, lgb, PTb, Rb);
    k_phaseB<<<dim3(NB*8),           blk, 0, stream>>>(PTb, Rb, Sb);
    k_phaseC<<<dim3(NB*NCHUNK),      blk, 0, stream>>>(qb, kb, vb, Mb, Sb, lgb, gb);
    k_out   <<<dim3(BTROWS/128, 16), blk, 0, stream>>>(gb, Wo, bo, (float*)d_out);
}

// Round 4
// 968.868 us; speedup vs baseline: 1.6220x; 1.1077x over previous
//
#include <hip/hip_runtime.h>
#include <hip/hip_bf16.h>
#include <math.h>

#define NB 16
#define NT 4096
#define ND 1024
#define NCC 128
#define LCH 64
#define NCHUNK 64
#define BTROWS 65536

typedef __bf16 v8bf __attribute__((ext_vector_type(8)));
typedef __bf16 v4bf __attribute__((ext_vector_type(4)));
typedef float  v4f  __attribute__((ext_vector_type(4)));

static __device__ __forceinline__ float sig_(float x){ return 1.0f/(1.0f + __expf(-x)); }
static __device__ __forceinline__ float dot4_(float4 a, float4 b){
    return a.x*b.x + a.y*b.y + a.z*b.z + a.w*b.w;
}

static __device__ __forceinline__ v8bf pack8(float4 a, float4 b){
    v8bf v;
    v[0]=(__bf16)a.x; v[1]=(__bf16)a.y; v[2]=(__bf16)a.z; v[3]=(__bf16)a.w;
    v[4]=(__bf16)b.x; v[5]=(__bf16)b.y; v[6]=(__bf16)b.z; v[7]=(__bf16)b.w;
    return v;
}

// async global->LDS, 16B per lane; lds dst is wave-uniform base (+lane*16 by HW)
static __device__ __forceinline__ void gload16(const void* g, void* l){
    __builtin_amdgcn_global_load_lds(
        (const __attribute__((address_space(1))) unsigned int*)g,
        (__attribute__((address_space(3))) unsigned int*)l, 16, 0, 0);
}

// ---------------- x -> bf16, fused alpha/beta GEMV ----------------
__global__ __launch_bounds__(256) void k_xcast(
    const float* __restrict__ x, const float* __restrict__ Wa,
    const float* __restrict__ Wb, const float* __restrict__ ba,
    const float* __restrict__ bb2, __bf16* __restrict__ xbf,
    float* __restrict__ ab, float* __restrict__ beb)
{
    const int tid = threadIdx.x;
    const int w = tid >> 6, lane = tid & 63;
    const size_t row = (size_t)blockIdx.x*4 + w;
    const float* xr = x + row*ND + lane*16;
    float4 f0 = ((const float4*)xr)[0];
    float4 f1 = ((const float4*)xr)[1];
    float4 f2 = ((const float4*)xr)[2];
    float4 f3 = ((const float4*)xr)[3];
    const float4* wa = (const float4*)(Wa + lane*16);
    const float4* wb = (const float4*)(Wb + lane*16);
    float da = dot4_(f0,wa[0]) + dot4_(f1,wa[1]) + dot4_(f2,wa[2]) + dot4_(f3,wa[3]);
    float db = dot4_(f0,wb[0]) + dot4_(f1,wb[1]) + dot4_(f2,wb[2]) + dot4_(f3,wb[3]);
    __bf16* xd = xbf + row*ND + lane*16;
    *(v8bf*)(xd)   = pack8(f0,f1);
    *(v8bf*)(xd+8) = pack8(f2,f3);
    #pragma unroll
    for (int m=1;m<64;m<<=1){ da += __shfl_xor(da,m,64); db += __shfl_xor(db,m,64); }
    if (lane == 0){
        ab[row]  = sig_(da + ba[0]);
        beb[row] = sig_(db + bb2[0]);
    }
}

// ---------------- W concat -> bf16 ----------------
__global__ __launch_bounds__(256) void k_wcast(
    const float* __restrict__ Wq, const float* __restrict__ Wk,
    const float* __restrict__ Wv, const float* __restrict__ Wg,
    __bf16* __restrict__ wbf)
{
    const int tid = threadIdx.x;
    const int w = tid >> 6, lane = tid & 63;
    const int row = blockIdx.x*4 + w;     // 0..511
    const float* src = (row < 128) ? Wq + (size_t)row*ND
                     : (row < 256) ? Wk + (size_t)(row-128)*ND
                     : (row < 384) ? Wv + (size_t)(row-256)*ND
                     :               Wg + (size_t)(row-384)*ND;
    const float4* s4 = (const float4*)(src + lane*16);
    float4 f0=s4[0], f1=s4[1], f2=s4[2], f3=s4[3];
    __bf16* xd = wbf + (size_t)row*ND + lane*16;
    *(v8bf*)(xd)   = pack8(f0,f1);
    *(v8bf*)(xd+8) = pack8(f2,f3);
}

// ---------------- GEMM1: [q k v g] = x_bf @ W_bf^T (m97 structure) ----------------
__global__ __launch_bounds__(256) void k_proj2(
    const __bf16* __restrict__ xbf, const __bf16* __restrict__ wbf,
    const float* __restrict__ bq, const float* __restrict__ bk,
    const float* __restrict__ bv, const float* __restrict__ bg,
    float* __restrict__ qb, float* __restrict__ kb2,
    float* __restrict__ vb, float* __restrict__ gb)
{
    __shared__ __attribute__((aligned(16))) __bf16 As[128*64];
    __shared__ __attribute__((aligned(16))) __bf16 Bs[128*64];
    const int tid = threadIdx.x;
    const int lane = tid & 63, w = tid >> 6;
    const int q4 = lane >> 4, l16 = lane & 15;
    const int wm = w >> 1, wn = w & 1;

    const int f = blockIdx.x;
    const int xcd = f & 7, j = f >> 3;
    const int m0 = ((xcd << 6) + (j >> 2)) * 128;
    const int n0 = (j & 3) * 128;

    v4f acc[4][4] = {};

    for (int k0 = 0; k0 < ND; k0 += 64){
        __syncthreads();
        #pragma unroll
        for (int i=0;i<4;i++){
            const int r  = (w*4+i)*8 + (lane >> 3);
            const int ce = (((lane & 7) ^ (r & 7)) << 3);   // pre-swizzled source col (elems)
            gload16(xbf + (size_t)(m0 + r)*ND + k0 + ce, (char*)As + (w*4+i)*1024);
            gload16(wbf + (size_t)(n0 + r)*ND + k0 + ce, (char*)Bs + (w*4+i)*1024);
        }
        __syncthreads();
        #pragma unroll
        for (int ks=0; ks<2; ks++){
            v8bf af[4], bf[4];
            #pragma unroll
            for (int mf=0; mf<4; mf++){
                const int r = wm*64 + mf*16 + l16;
                af[mf] = *(const v8bf*)((const char*)As + r*128 + (((ks*4+q4) ^ (r&7)) << 4));
            }
            #pragma unroll
            for (int nf=0; nf<4; nf++){
                const int r = wn*64 + nf*16 + l16;
                bf[nf] = *(const v8bf*)((const char*)Bs + r*128 + (((ks*4+q4) ^ (r&7)) << 4));
            }
            #pragma unroll
            for (int mf=0; mf<4; mf++)
                #pragma unroll
                for (int nf=0; nf<4; nf++)
                    acc[mf][nf] = __builtin_amdgcn_mfma_f32_16x16x32_bf16(af[mf], bf[nf], acc[mf][nf], 0,0,0);
        }
    }

    #pragma unroll
    for (int mf=0; mf<4; mf++){
        #pragma unroll
        for (int nf=0; nf<4; nf++){
            const int ng  = n0 + wn*64 + nf*16 + l16;   // 0..511
            const int col = ng & 127;
            const int sel = ng >> 7;
            const float bias = (sel==0) ? bq[col] : (sel==1) ? bk[col]
                             : (sel==2) ? bv[col] : bg[col];
            #pragma unroll
            for (int r2=0;r2<4;r2++){
                const int m = m0 + wm*64 + mf*16 + q4*4 + r2;
                const float val = acc[mf][nf][r2] + bias;
                const size_t off = (size_t)m*NCC + col;
                if      (sel == 0) qb[off]  = val;
                else if (sel == 1) kb2[off] = val;
                else if (sel == 2) vb[off]  = val;
                else               gb[off]  = sig_(val);
            }
        }
    }
}

// ---------------- normalize k rows ----------------
__global__ __launch_bounds__(256) void k_knorm(float* __restrict__ kb){
    const int tid = threadIdx.x;
    const int w = tid >> 6, lane = tid & 63;
    const size_t row = (size_t)blockIdx.x*4 + w;
    float* kr = kb + row*NCC;
    float a = kr[lane], b = kr[lane+64];
    float ss = a*a + b*b;
    #pragma unroll
    for (int m=1;m<64;m<<=1) ss += __shfl_xor(ss, m, 64);
    float inv = 1.0f / fmaxf(sqrtf(ss), 1e-12f);
    kr[lane] = a*inv; kr[lane+64] = b*inv;
}

// ---------------- Phase A: per-chunk precompute ----------------
// LDS 66KB -> 2 blocks/CU. K staged as bf16 hi/lo (f32-accurate via split),
// V loaded straight into the register solve column, G-gram via split MFMA,
// P^T/R via MFMA with operand-swapped vectorized stores.
#define TSW(r, g)  ((r)*64 + ((((g) ^ ((r)&7))) << 3))   // bf16 pitch-64, 8-elem granules

static __device__ __forceinline__ int kswz(int t, int g){ // granule g (0..15) of row t
    return t*128 + (((g & 8) | ((g & 7) ^ (t & 7))) << 3);
}

__global__ __launch_bounds__(256, 2) void k_phaseA(
    const float* __restrict__ kb, float* __restrict__ vb, __bf16* __restrict__ Mb,
    const float* __restrict__ ab, const float* __restrict__ beb,
    float* __restrict__ lgb, __bf16* __restrict__ PTb, float* __restrict__ Rb)
{
    __shared__ __attribute__((aligned(16))) char SM[67584];
    __bf16* KH  = (__bf16*)(SM);            // 64x128 bf16 hi, granule-swizzled
    __bf16* KL  = (__bf16*)(SM + 16384);    // lo; reused as KT after solve
    float*  Gsh = (float*) (SM + 32768);    // 64x68 f32; reused as EUT after solve
    __bf16* EMT = (__bf16*)(SM + 50176);    // 128x64 bf16, TSW
    float*  lgs = (float*) (SM + 66560);
    float*  bsh = (float*) (SM + 66816);
    float*  esh = (float*) (SM + 67072);
    float*  gam = (float*) (SM + 67328);
    __bf16* KT  = (__bf16*)(SM + 16384);
    __bf16* EUT = (__bf16*)(SM + 32768);

    const int tid = threadIdx.x;
    const int b = blockIdx.x >> 6, c = blockIdx.x & 63;
    const size_t base = (size_t)b*NT + (size_t)c*LCH;
    const int lane = tid & 63, w = tid >> 6;
    const int q4 = lane >> 4, l16 = lane & 15;
    const int half = tid >> 7, cix = tid & 127;

    // solve column lives in registers; starts as the RHS
    float u[64];
    if (half == 0){
        #pragma unroll
        for (int t=0;t<64;t++) u[t] = vb[(base+t)*NCC + cix];   // RHS = v
    }

    if (tid < LCH){
        float la = __logf(fmaxf(ab[base+tid], 1e-30f));
        float ps = la;
        #pragma unroll
        for (int off=1; off<64; off<<=1){
            float o = __shfl_up(ps, off, 64);
            if ((tid & 63) >= off) ps += o;
        }
        lgs[tid] = ps;
        bsh[tid] = beb[base+tid];
    }
    // stage K hi/lo (granule-swizzled)
    {
        const int row = tid >> 2, seg = tid & 3;
        const float* ksr = kb + (base+row)*NCC + seg*32;
        #pragma unroll
        for (int gs=0; gs<4; gs++){
            float4 a = *(const float4*)(ksr + gs*8);
            float4 d = *(const float4*)(ksr + gs*8 + 4);
            v8bf hi = pack8(a,d);
            v8bf lo;
            lo[0]=(__bf16)(a.x-(float)hi[0]); lo[1]=(__bf16)(a.y-(float)hi[1]);
            lo[2]=(__bf16)(a.z-(float)hi[2]); lo[3]=(__bf16)(a.w-(float)hi[3]);
            lo[4]=(__bf16)(d.x-(float)hi[4]); lo[5]=(__bf16)(d.y-(float)hi[5]);
            lo[6]=(__bf16)(d.z-(float)hi[6]); lo[7]=(__bf16)(d.w-(float)hi[7]);
            const int off = kswz(row, seg*4+gs);
            *(v8bf*)(&KH[off]) = hi;
            *(v8bf*)(&KL[off]) = lo;
        }
    }
    __syncthreads();
    if (tid < LCH){
        lgb[base+tid] = lgs[tid];
        esh[tid] = __expf(lgs[LCH-1] - lgs[tid]);
        gam[tid] = __expf(lgs[tid]);
    }
    // Gram via split MFMA: G[t][s] = exp(lgs[t]-lgs[s]) * (k_t . k_s), s <= t
    if (w != 1){   // wave 1's quadrant (t<32, s>=32) is all-upper -> idle
        const int wt = w >> 1, ws2 = w & 1;
        v4f g2[2][2] = {};
        #pragma unroll
        for (int ks=0; ks<4; ks++){
            v8bf ah[2], al[2], bh[2], bl[2];
            #pragma unroll
            for (int mf=0; mf<2; mf++){
                const int r = wt*32 + mf*16 + l16;
                const int off = kswz(r, ks*4+q4);
                ah[mf] = *(const v8bf*)(&KH[off]);
                al[mf] = *(const v8bf*)(&KL[off]);
            }
            #pragma unroll
            for (int nf=0; nf<2; nf++){
                const int r = ws2*32 + nf*16 + l16;
                const int off = kswz(r, ks*4+q4);
                bh[nf] = *(const v8bf*)(&KH[off]);
                bl[nf] = *(const v8bf*)(&KL[off]);
            }
            #pragma unroll
            for (int mf=0; mf<2; mf++)
                #pragma unroll
                for (int nf=0; nf<2; nf++){
                    g2[mf][nf] = __builtin_amdgcn_mfma_f32_16x16x32_bf16(al[mf], bh[nf], g2[mf][nf], 0,0,0);
                    g2[mf][nf] = __builtin_amdgcn_mfma_f32_16x16x32_bf16(ah[mf], bl[nf], g2[mf][nf], 0,0,0);
                    g2[mf][nf] = __builtin_amdgcn_mfma_f32_16x16x32_bf16(ah[mf], bh[nf], g2[mf][nf], 0,0,0);
                }
        }
        #pragma unroll
        for (int mf=0; mf<2; mf++){
            #pragma unroll
            for (int nf=0; nf<2; nf++){
                #pragma unroll
                for (int r=0;r<4;r++){
                    const int t = wt*32 + mf*16 + q4*4 + r;
                    const int s = ws2*32 + nf*16 + l16;
                    if (s <= t) Gsh[t*68+s] = __expf(lgs[t]-lgs[s])*g2[mf][nf][r];
                }
            }
        }
    }
    __syncthreads();

    // RHS for the M column: gam_t * k_t[cix]  (f32 via hi+lo)
    if (half == 1){
        const int gc = cix >> 3, ge = cix & 7;
        #pragma unroll
        for (int t=0;t<64;t++){
            const int off = t*128 + (((gc&8) | ((gc&7)^(t&7))) << 3) + ge;
            u[t] = gam[t]*((float)KH[off] + (float)KL[off]);
        }
    }
    // barrier-free forward substitution (register column, unrolled)
    #pragma unroll
    for (int t=0;t<64;t++){
        const float* Gr = &Gsh[t*68];
        float s0=0.f,s1=0.f,s2=0.f,s3=0.f;
        #pragma unroll
        for (int s4=0; s4+4<=t; s4+=4){
            float4 g = *(const float4*)(Gr+s4);
            s0 += g.x*u[s4]; s1 += g.y*u[s4+1]; s2 += g.z*u[s4+2]; s3 += g.w*u[s4+3];
        }
        #pragma unroll
        for (int s=(t & ~3); s<t; s++) s0 += Gr[s]*u[s];
        u[t] = bsh[t]*(u[t] - ((s0+s1)+(s2+s3)));
    }
    if (half == 0){
        #pragma unroll
        for (int t=0;t<64;t++) vb[(base+t)*NCC + cix] = u[t];       // U over v
    } else {
        #pragma unroll
        for (int t=0;t<64;t++) Mb[(base+t)*NCC + cix] = (__bf16)u[t];
    }
    __syncthreads();   // Gsh / KL reads complete -> reuse as EUT / KT

    // EUT/EMT (e-scaled, transposed, TSW) and KT (from KH)
    {
        if (half == 0){
            #pragma unroll
            for (int g=0; g<8; g++){
                v8bf pk;
                #pragma unroll
                for (int e=0;e<8;e++) pk[e] = (__bf16)(esh[g*8+e]*u[g*8+e]);
                *(v8bf*)(&EUT[TSW(cix, g)]) = pk;
            }
        } else {
            #pragma unroll
            for (int g=0; g<8; g++){
                v8bf pk;
                #pragma unroll
                for (int e=0;e<8;e++) pk[e] = (__bf16)(esh[g*8+e]*u[g*8+e]);
                *(v8bf*)(&EMT[TSW(cix, g)]) = pk;
            }
        }
        const int j = cix, gc = j >> 3, ge = j & 7;
        #pragma unroll
        for (int g2b=0; g2b<4; g2b++){
            const int tg = half*4 + g2b, t0 = tg*8;
            v8bf pk;
            #pragma unroll
            for (int e=0;e<8;e++)
                pk[e] = KH[(t0+e)*128 + (((gc&8) | ((gc&7)^((t0+e)&7))) << 3) + ge];
            *(v8bf*)(&KT[TSW(j, tg)]) = pk;
        }
    }
    __syncthreads();

    const int wm = w >> 1, wn = w & 1;
    const float gl = gam[LCH-1];
    const size_t pbase = ((size_t)(b*NCHUNK + c))*NCC*NCC;
    // P^T[j][m] = gl*delta - sum_t EMT[m][t]*KT[j][t]   (A=EMT: rows m; B=KT: cols j)
    {
        v4f pacc[4][4] = {};
        #pragma unroll
        for (int ks=0; ks<2; ks++){
            v8bf af[4], bf[4];
            #pragma unroll
            for (int mf=0; mf<4; mf++)
                af[mf] = *(const v8bf*)(&EMT[TSW(wm*64+mf*16+l16, ks*4+q4)]);
            #pragma unroll
            for (int nf=0; nf<4; nf++)
                bf[nf] = *(const v8bf*)(&KT[TSW(wn*64+nf*16+l16, ks*4+q4)]);
            #pragma unroll
            for (int mf=0; mf<4; mf++)
                #pragma unroll
                for (int nf=0; nf<4; nf++)
                    pacc[mf][nf] = __builtin_amdgcn_mfma_f32_16x16x32_bf16(af[mf], bf[nf], pacc[mf][nf], 0,0,0);
        }
        #pragma unroll
        for (int mf=0; mf<4; mf++){
            #pragma unroll
            for (int nf=0; nf<4; nf++){
                const int m0 = wm*64 + mf*16 + q4*4;
                const int j  = wn*64 + nf*16 + l16;
                v4bf pk;
                #pragma unroll
                for (int r=0;r<4;r++){
                    float v = -pacc[mf][nf][r];
                    if (j == m0+r) v += gl;
                    pk[r] = (__bf16)v;
                }
                *(v4bf*)(PTb + pbase + (size_t)j*NCC + m0) = pk;
            }
        }
    }
    // R[i][j] = sum_t EUT[i][t]*KT[j][t]   (A=KT: rows j; B=EUT: cols i)
    {
        v4f racc[4][4] = {};
        #pragma unroll
        for (int ks=0; ks<2; ks++){
            v8bf af[4], bf[4];
            #pragma unroll
            for (int mf=0; mf<4; mf++)
                af[mf] = *(const v8bf*)(&KT[TSW(wm*64+mf*16+l16, ks*4+q4)]);
            #pragma unroll
            for (int nf=0; nf<4; nf++)
                bf[nf] = *(const v8bf*)(&EUT[TSW(wn*64+nf*16+l16, ks*4+q4)]);
            #pragma unroll
            for (int mf=0; mf<4; mf++)
                #pragma unroll
                for (int nf=0; nf<4; nf++)
                    racc[mf][nf] = __builtin_amdgcn_mfma_f32_16x16x32_bf16(af[mf], bf[nf], racc[mf][nf], 0,0,0);
        }
        #pragma unroll
        for (int mf=0; mf<4; mf++){
            #pragma unroll
            for (int nf=0; nf<4; nf++){
                const int j0 = wm*64 + mf*16 + q4*4;
                const int i  = wn*64 + nf*16 + l16;
                float4 fv = make_float4(racc[mf][nf][0], racc[mf][nf][1],
                                        racc[mf][nf][2], racc[mf][nf][3]);
                *(float4*)(Rb + pbase + (size_t)i*NCC + j0) = fv;
            }
        }
    }
}

// ---------------- Phase B: S <- S*P + R over chunks; rows independent ----------------
__global__ __launch_bounds__(256) void k_phaseB(
    const __bf16* __restrict__ PTb, const float* __restrict__ Rb, float* __restrict__ Sb)
{
    __shared__ __attribute__((aligned(16))) float Ssh[16*132];
    const int tid = threadIdx.x;
    const int b = blockIdx.x >> 3, rb = blockIdx.x & 7;
    const int r0 = rb*16;
    const int lane = tid & 63, w = tid >> 6;
    const int q4 = lane >> 4, l16 = lane & 15;
    for (int i=tid; i<16*132; i+=256) Ssh[i] = 0.f;
    __syncthreads();
    for (int c=0; c<NCHUNK; c++){
        const size_t pbase = ((size_t)(b*NCHUNK + c))*NCC*NCC;
        {
            const int row = tid >> 4, cg = (tid & 15)*8;
            float* dst = Sb + pbase + (size_t)(r0+row)*NCC + cg;
            *(float4*)(dst)   = *(const float4*)(&Ssh[row*132+cg]);
            *(float4*)(dst+4) = *(const float4*)(&Ssh[row*132+cg+4]);
        }
        if (c == NCHUNK-1) break;
        v8bf af[4];
        #pragma unroll
        for (int ks=0; ks<4; ks++){
            const float* sr = &Ssh[l16*132 + ks*32 + q4*8];
            v8bf t;
            #pragma unroll
            for (int j=0;j<8;j++) t[j] = (__bf16)sr[j];
            af[ks] = t;
        }
        __syncthreads();
        v4f acc[2] = {};
        #pragma unroll
        for (int nt=0; nt<2; nt++){
            const int n0 = w*32 + nt*16;
            #pragma unroll
            for (int ks=0; ks<4; ks++){
                v8bf bf = *(const v8bf*)(PTb + pbase + (size_t)(n0+l16)*NCC + ks*32 + q4*8);
                acc[nt] = __builtin_amdgcn_mfma_f32_16x16x32_bf16(af[ks], bf, acc[nt], 0,0,0);
            }
        }
        #pragma unroll
        for (int nt=0; nt<2; nt++){
            const int n = w*32 + nt*16 + l16;
            #pragma unroll
            for (int r=0;r<4;r++){
                const int rowl = q4*4 + r;
                Ssh[rowl*132 + n] = acc[nt][r] + Rb[pbase + (size_t)(r0+rowl)*NCC + n];
            }
        }
        __syncthreads();
    }
}

// ---------------- Phase C: per-chunk outputs (MFMA) ----------------
__global__ __launch_bounds__(256) void k_phaseC(
    const float* __restrict__ qb, const float* __restrict__ kb,
    const float* __restrict__ Ub, const __bf16* __restrict__ Mb,
    const float* __restrict__ Sb, const float* __restrict__ lgb,
    float* __restrict__ gb)
{
    __shared__ __attribute__((aligned(16))) __bf16 S0r[NCC*136];  // S0 rows (bf16)
    __shared__ __attribute__((aligned(16))) __bf16 S0t[NCC*136];  // S0^T rows (bf16)
    __shared__ __attribute__((aligned(16))) __bf16 MA [LCH*136];  // Msh, then Ash (pitch 72, TSWZ)
    __shared__ __attribute__((aligned(16))) __bf16 Wsh[LCH*136];
    __shared__ __attribute__((aligned(16))) __bf16 KT [NCC*72];   // K^T[j][s], TSWZ
    __shared__ float lgs[LCH];

    const int tid = threadIdx.x;
    const int b = blockIdx.x >> 6, c = blockIdx.x & 63;
    const size_t base = (size_t)b*NT + (size_t)c*LCH;
    const size_t pbase = ((size_t)(b*NCHUNK + c))*NCC*NCC;
    const int lane = tid & 63, w = tid >> 6;
    const int q4 = lane >> 4, l16 = lane & 15;

    if (tid < LCH) lgs[tid] = lgb[base+tid];
    // S0 staging: bf16 rows + bf16 transpose
    {
        const int i = tid >> 1, jh = (tid & 1)*64;
        const float* src = Sb + pbase + (size_t)i*NCC + jh;
        #pragma unroll
        for (int g=0; g<8; g++){
            float4 a = *(const float4*)(src + g*8);
            float4 d = *(const float4*)(src + g*8 + 4);
            v8bf pk = pack8(a,d);
            *(v8bf*)(&S0r[i*136 + jh + g*8]) = pk;
            #pragma unroll
            for (int e=0;e<8;e++) S0t[(jh + g*8 + e)*136 + i] = pk[e];
        }
    }
    // M rows (bf16 global -> LDS, straight copy)
    {
        const int row = tid >> 2, seg = (tid & 3)*32;
        const __bf16* ms = Mb + (base+row)*NCC + seg;
        *(v8bf*)(&MA[row*136 + seg])      = *(const v8bf*)(ms);
        *(v8bf*)(&MA[row*136 + seg + 8])  = *(const v8bf*)(ms+8);
        *(v8bf*)(&MA[row*136 + seg + 16]) = *(const v8bf*)(ms+16);
        *(v8bf*)(&MA[row*136 + seg + 24]) = *(const v8bf*)(ms+24);
    }
    // K -> KT (transposed, TSWZ); coalesced row reads
    {
        const int j = tid & 127, th = tid >> 7;
        #pragma unroll
        for (int g=0; g<4; g++){
            const int sg = th*4 + g;
            const int s0 = sg*8;
            v8bf pk;
            #pragma unroll
            for (int e=0;e<8;e++) pk[e] = (__bf16)kb[(base+s0+e)*NCC + j];
            *(v8bf*)(&KT[(j)*72 + ((((sg) ^ ((j)&7))) << 3)]) = pk;
        }
    }
    // Q fragments in registers (A-operand for O2 and X2; contraction over i)
    v8bf qf[4];
    #pragma unroll
    for (int ks=0; ks<4; ks++){
        const float* qs = qb + (base + w*16 + l16)*NCC + ks*32 + q4*8;
        float4 a = *(const float4*)(qs);
        float4 d = *(const float4*)(qs+4);
        qf[ks] = pack8(a,d);
    }
    __syncthreads();

    // X1 = M S0^T ; W = U - X1 -> Wsh
    {
        v4f x1[8] = {};
        #pragma unroll
        for (int ks=0; ks<4; ks++){
            v8bf af = *(const v8bf*)(&MA[(w*16+l16)*136 + ks*32 + q4*8]);
            #pragma unroll
            for (int ib=0; ib<8; ib++){
                v8bf bf = *(const v8bf*)(&S0r[(ib*16+l16)*136 + ks*32 + q4*8]);
                x1[ib] = __builtin_amdgcn_mfma_f32_16x16x32_bf16(af, bf, x1[ib], 0,0,0);
            }
        }
        #pragma unroll
        for (int ib=0; ib<8; ib++){
            #pragma unroll
            for (int r=0;r<4;r++){
                const int t = w*16 + q4*4 + r;
                const int i = ib*16 + l16;
                const float u = Ub[(base+t)*NCC + i];
                Wsh[t*136 + i] = (__bf16)(u - x1[ib][r]);
            }
        }
    }
    // O2 = Q S0 (registers; gamma applied at epilogue)
    v4f o2[8] = {};
    #pragma unroll
    for (int ks=0; ks<4; ks++){
        #pragma unroll
        for (int jb=0; jb<8; jb++){
            v8bf bf = *(const v8bf*)(&S0t[(jb*16+l16)*136 + ks*32 + q4*8]);
            o2[jb] = __builtin_amdgcn_mfma_f32_16x16x32_bf16(qf[ks], bf, o2[jb], 0,0,0);
        }
    }
    __syncthreads();   // Wsh ready; MA (Msh) reads complete -> can be overwritten as Ash

    // X2 = Q W^T -> A = tril_incl(exp(lg_t-lg_s) * X2), bf16, into MA (pitch 72, TSWZ)
    {
        v4f x2[4] = {};
        #pragma unroll
        for (int ks=0; ks<4; ks++){
            #pragma unroll
            for (int sb=0; sb<4; sb++){
                v8bf bf = *(const v8bf*)(&Wsh[(sb*16+l16)*136 + ks*32 + q4*8]);
                x2[sb] = __builtin_amdgcn_mfma_f32_16x16x32_bf16(qf[ks], bf, x2[sb], 0,0,0);
            }
        }
        #pragma unroll
        for (int sb=0; sb<4; sb++){
            #pragma unroll
            for (int r=0;r<4;r++){
                const int t = w*16 + q4*4 + r;
                const int s = sb*16 + l16;
                const float v = (s <= t) ? __expf(lgs[t]-lgs[s])*x2[sb][r] : 0.f;
                MA[t*72 + ((((s>>3) ^ (t&7))) << 3) + (s&7)] = (__bf16)v;
            }
        }
    }
    __syncthreads();   // Ash ready

    // O1 = A K ; o = (O1 + gamma*O2) * gate -> gb in place
    {
        v4f o1[8] = {};
        #pragma unroll
        for (int ks=0; ks<2; ks++){
            v8bf af = *(const v8bf*)(&MA[(w*16+l16)*72 + ((((ks*4+q4) ^ ((w*16+l16)&7))) << 3)]);
            #pragma unroll
            for (int jb=0; jb<8; jb++){
                v8bf bf = *(const v8bf*)(&KT[(jb*16+l16)*72 + ((((ks*4+q4) ^ ((jb*16+l16)&7))) << 3)]);
                o1[jb] = __builtin_amdgcn_mfma_f32_16x16x32_bf16(af, bf, o1[jb], 0,0,0);
            }
        }
        float gam4[4];
        #pragma unroll
        for (int r=0;r<4;r++) gam4[r] = __expf(lgs[w*16 + q4*4 + r]);
        #pragma unroll
        for (int jb=0; jb<8; jb++){
            #pragma unroll
            for (int r=0;r<4;r++){
                const int t = w*16 + q4*4 + r;
                const int j = jb*16 + l16;
                const size_t off = (size_t)(base+t)*NCC + j;
                gb[off] = (o1[jb][r] + gam4[r]*o2[jb][r]) * gb[off];
            }
        }
    }
}

// ---------------- GEMM2: out = obar @ Wo^T + bo ----------------
__global__ __launch_bounds__(256) void k_out(
    const float* __restrict__ ob, const float* __restrict__ Wo,
    const float* __restrict__ bo, float* __restrict__ out)
{
    __shared__ __attribute__((aligned(16))) __bf16 As[128*40];
    __shared__ __attribute__((aligned(16))) __bf16 Bs[64*40];
    const int tid = threadIdx.x;
    const int m0 = blockIdx.x*128, n0 = blockIdx.y*64;
    const int lane = tid & 63, w = tid >> 6;
    const int q4 = lane >> 4, l16 = lane & 15;
    const int arow = tid >> 1, aseg = tid & 1;
    const int brow = tid >> 2, bseg = tid & 3;
    const float* asrc = ob + (size_t)(m0+arow)*NCC;
    const float* bsrc = Wo + (size_t)(n0+brow)*NCC;

    v4f acc[2][4] = {};

    for (int k0=0; k0<NCC; k0+=32){
        __syncthreads();
        {
            float4 f0 = *(const float4*)(asrc + k0 + aseg*16);
            float4 f1 = *(const float4*)(asrc + k0 + aseg*16 + 4);
            float4 f2 = *(const float4*)(asrc + k0 + aseg*16 + 8);
            float4 f3 = *(const float4*)(asrc + k0 + aseg*16 + 12);
            *(v8bf*)(&As[arow*40 + aseg*16])     = pack8(f0,f1);
            *(v8bf*)(&As[arow*40 + aseg*16 + 8]) = pack8(f2,f3);
        }
        {
            float4 g0 = *(const float4*)(bsrc + k0 + bseg*8);
            float4 g1 = *(const float4*)(bsrc + k0 + bseg*8 + 4);
            *(v8bf*)(&Bs[brow*40 + bseg*8]) = pack8(g0,g1);
        }
        __syncthreads();
        v8bf af0 = *(const v8bf*)(&As[(w*32 + l16)*40 + q4*8]);
        v8bf af1 = *(const v8bf*)(&As[(w*32 + 16 + l16)*40 + q4*8]);
        #pragma unroll
        for (int nt=0; nt<4; nt++){
            v8bf bf = *(const v8bf*)(&Bs[(nt*16 + l16)*40 + q4*8]);
            acc[0][nt] = __builtin_amdgcn_mfma_f32_16x16x32_bf16(af0, bf, acc[0][nt], 0,0,0);
            acc[1][nt] = __builtin_amdgcn_mfma_f32_16x16x32_bf16(af1, bf, acc[1][nt], 0,0,0);
        }
    }
    #pragma unroll
    for (int mt=0; mt<2; mt++){
        #pragma unroll
        for (int nt=0; nt<4; nt++){
            const int n = n0 + nt*16 + l16;
            const float bias = bo[n];
            #pragma unroll
            for (int r=0;r<4;r++){
                const int m = m0 + w*32 + mt*16 + q4*4 + r;
                out[(size_t)m*ND + n] = acc[mt][nt][r] + bias;
            }
        }
    }
}

extern "C" void kernel_launch(void* const* d_in, const int* in_sizes, int n_in,
                              void* d_out, int out_size, void* d_ws, size_t ws_size,
                              hipStream_t stream)
{
    const float* x  = (const float*)d_in[0];
    const float* Wq = (const float*)d_in[1];
    const float* bq = (const float*)d_in[2];
    const float* Wk = (const float*)d_in[3];
    const float* bk = (const float*)d_in[4];
    const float* Wv = (const float*)d_in[5];
    const float* bv = (const float*)d_in[6];
    const float* Wa = (const float*)d_in[7];
    const float* ba = (const float*)d_in[8];
    const float* Wb = (const float*)d_in[9];
    const float* bb2= (const float*)d_in[10];
    const float* Wg = (const float*)d_in[11];
    const float* bg = (const float*)d_in[12];
    const float* Wo = (const float*)d_in[13];
    const float* bo = (const float*)d_in[14];

    char* ws = (char*)d_ws;
    const size_t SZ = (size_t)BTROWS*NCC*4;     // 33.55 MB
    float*  qb  = (float*)(ws + 0*SZ);
    float*  kb  = (float*)(ws + 1*SZ);
    float*  vb  = (float*)(ws + 2*SZ);          // v, overwritten by U
    __bf16* Mb  = (__bf16*)(ws + 3*SZ);         // bf16 M (half of slot used)
    float*  gb  = (float*)(ws + 4*SZ);          // gate, overwritten by obar
    float*  Sb  = (float*)(ws + 5*SZ);          // 2*SZ: per-chunk incoming states
    float*  Rb  = (float*)(ws + 7*SZ);          // 2*SZ
    __bf16* PTb = (__bf16*)(ws + 9*SZ);         // SZ bytes (bf16)
    float*  ab  = (float*)(ws + 10*SZ);
    float*  beb = (float*)(ws + 10*SZ + 262144);
    float*  lgb = (float*)(ws + 10*SZ + 524288);
    // transient (pre-phaseA) reuse of Sb/Rb/PTb region:
    __bf16* xbf = (__bf16*)(ws + 5*SZ);         // 4*SZ bytes (65536x1024 bf16) = slots 5..9
    __bf16* wbf = (__bf16*)(ws + 9*SZ);         // 1 MB (512x1024 bf16), freed before phaseA writes PTb
    if (ws_size < 10*SZ + 786432) return;       // insufficient workspace

    dim3 blk(256);
    k_wcast <<<dim3(128),            blk, 0, stream>>>(Wq,Wk,Wv,Wg,wbf);
    k_xcast <<<dim3(BTROWS/4),       blk, 0, stream>>>(x,Wa,Wb,ba,bb2,xbf,ab,beb);
    k_proj2 <<<dim3(2048),           blk, 0, stream>>>(xbf,wbf,bq,bk,bv,bg,qb,kb,vb,gb);
    k_knorm <<<dim3(BTROWS/4),       blk, 0, stream>>>(kb);
    k_phaseA<<<dim3(NB*NCHUNK),      blk, 0, stream>>>(kb, vb, Mb, ab, beb, lgb, PTb, Rb);
    k_phaseB<<<dim3(NB*8),           blk, 0, stream>>>(PTb, Rb, Sb);
    k_phaseC<<<dim3(NB*NCHUNK),      blk, 0, stream>>>(qb, kb, vb, Mb, Sb, lgb, gb);
    k_out   <<<dim3(BTROWS/128, 16), blk, 0, stream>>>(gb, Wo, bo, (float*)d_out);
}